// Round 1
// baseline (400.236 us; speedup 1.0000x reference)
//
#include <hip/hip_runtime.h>
#include <hip/hip_bf16.h>
#include <cstdint>

__device__ __forceinline__ float lrelu02(float x){ return x > 0.f ? x : 0.2f*x; }
__device__ __forceinline__ float elu1(float x){ return x > 0.f ? x : expm1f(x); }

__device__ __forceinline__ float wave_reduce_sum(float v){
  #pragma unroll
  for (int o = 32; o >= 1; o >>= 1) v += __shfl_xor(v, o, 64);
  return v;
}
__device__ __forceinline__ float wave_reduce_max(float v){
  #pragma unroll
  for (int o = 32; o >= 1; o >>= 1) v = fmaxf(v, __shfl_xor(v, o, 64));
  return v;
}

// ---------------- CSR build ----------------
__global__ void hist_kernel(const int* __restrict__ ei, int* __restrict__ cnt, int E){
  int e = blockIdx.x*blockDim.x + threadIdx.x;
  if (e < E) atomicAdd(&cnt[ei[E + e]], 1);
}

__global__ void scan_kernel(const int* __restrict__ cnt, int* __restrict__ rp, int N){
  __shared__ int part[1024];
  const int PER = 16;
  int t = threadIdx.x;
  int base = t*PER;
  int local[PER]; int s = 0;
  #pragma unroll
  for (int i=0;i<PER;i++){ int idx=base+i; int v = (idx<N)? cnt[idx] : 0; local[i]=s; s+=v; }
  part[t]=s; __syncthreads();
  for (int off=1; off<1024; off<<=1){
    int v = (t>=off)? part[t-off] : 0;
    __syncthreads();
    part[t] += v;
    __syncthreads();
  }
  int ex = (t>0)? part[t-1] : 0;
  #pragma unroll
  for (int i=0;i<PER;i++){ int idx=base+i; if (idx<N) rp[idx] = ex + local[i]; }
  if (t==0) rp[N] = part[1023];
}

__global__ void fill_kernel(const int* __restrict__ ei, const int* __restrict__ rp,
                            int* __restrict__ fl, int* __restrict__ col, int E){
  int e = blockIdx.x*blockDim.x + threadIdx.x;
  if (e >= E) return;
  int d = ei[E+e];
  int pos = rp[d] + atomicAdd(&fl[d], 1);
  col[pos] = ei[e];
}

// ---------------- generic f32 tiled GEMM: C[M,N] = A[M,K] @ B[K,N] (+bias, opt ReLU)
template<int RELU>
__global__ __launch_bounds__(256) void gemm_kernel(
    const float* __restrict__ A, const float* __restrict__ B,
    const float* __restrict__ bias, float* __restrict__ C,
    int M, int N, int K){
  const int BM=64, BN=64, BK=32;
  __shared__ float As[BK][BM+4];
  __shared__ float Bs[BK][BN+4];
  int tid = threadIdx.x;
  int tx = tid & 15, ty = tid >> 4;
  int row0 = blockIdx.y*BM, col0 = blockIdx.x*BN;
  float acc[4][4] = {};
  for (int k0=0; k0<K; k0+=BK){
    #pragma unroll
    for (int i=0;i<8;i++){
      int idx = i*256 + tid;
      int k = idx & 31, m = idx >> 5;
      int gr = row0+m, gk = k0+k;
      As[k][m] = (gr<M && gk<K)? A[(size_t)gr*K+gk] : 0.f;
    }
    #pragma unroll
    for (int i=0;i<8;i++){
      int idx = i*256 + tid;
      int n = idx & 63, k = idx >> 6;
      int gk = k0+k, gn = col0+n;
      Bs[k][n] = (gk<K && gn<N)? B[(size_t)gk*N+gn] : 0.f;
    }
    __syncthreads();
    #pragma unroll
    for (int k=0;k<BK;k++){
      float4 av = *(const float4*)&As[k][ty*4];
      float4 bv = *(const float4*)&Bs[k][tx*4];
      const float* ap = (const float*)&av;
      const float* bp = (const float*)&bv;
      #pragma unroll
      for (int i=0;i<4;i++)
        #pragma unroll
        for (int j=0;j<4;j++)
          acc[i][j] += ap[i]*bp[j];
    }
    __syncthreads();
  }
  #pragma unroll
  for (int i=0;i<4;i++){
    int r = row0 + ty*4 + i;
    if (r >= M) continue;
    #pragma unroll
    for (int j=0;j<4;j++){
      int c = col0 + tx*4 + j;
      if (c >= N) continue;
      float v = acc[i][j] + (bias? bias[c] : 0.f);
      if (RELU) v = fmaxf(v, 0.f);
      C[(size_t)r*N + c] = v;
    }
  }
}

// ---------------- attention coefficients: one wave per (node, head), C=128
template<int H>
__global__ void attn_kernel(const float* __restrict__ h,
                            const float* __restrict__ att_src,
                            const float* __restrict__ att_dst,
                            float* __restrict__ asrc, float* __restrict__ adst, int N){
  const int C = 128;
  int lane = threadIdx.x & 63;
  int w = blockIdx.x*4 + (threadIdx.x >> 6);
  if (w >= N*H) return;
  int hh = w % H;
  const float* hp = h + (size_t)w*C;   // layout [N,H,C]: (n*H+hh)*C == w*C
  float s = hp[lane]*att_src[hh*C+lane] + hp[lane+64]*att_src[hh*C+lane+64];
  float d = hp[lane]*att_dst[hh*C+lane] + hp[lane+64]*att_dst[hh*C+lane+64];
  s = wave_reduce_sum(s); d = wave_reduce_sum(d);
  if (lane==0){ asrc[w]=s; adst[w]=d; }
}

// ---------------- GAT aggregation: one wave per (node, head), C=128
// softmax over incoming edges + self loop, out = elu(sum alpha*h[src] + bias)
template<int H>
__global__ void agg_kernel(const float* __restrict__ h,
                           const float* __restrict__ asrc,
                           const float* __restrict__ adst,
                           const float* __restrict__ bias,
                           const int* __restrict__ rp,
                           const int* __restrict__ col,
                           float* __restrict__ out, int N){
  const int C = 128;
  int lane = threadIdx.x & 63;
  int w = blockIdx.x*4 + (threadIdx.x >> 6);
  if (w >= N*H) return;
  int n = w / H, hh = w % H;
  int beg = rp[n], end = rp[n+1];
  float adst_i = adst[w];
  float s_self = lrelu02(asrc[w] + adst_i);
  // pass 1: max
  float m = s_self;
  for (int e = beg+lane; e < end; e += 64){
    m = fmaxf(m, lrelu02(asrc[col[e]*H + hh] + adst_i));
  }
  m = wave_reduce_max(m);
  // pass 2: sum of exp
  float ssum = (lane==0)? expf(s_self - m) : 0.f;
  for (int e = beg+lane; e < end; e += 64){
    ssum += expf(lrelu02(asrc[col[e]*H + hh] + adst_i) - m);
  }
  ssum = wave_reduce_sum(ssum);
  float inv = 1.f / fmaxf(ssum, 1e-16f);
  // pass 3: weighted accumulate (serial over edges, 1-deep prefetch)
  const float* hp = h + (size_t)w*C;
  float wself = expf(s_self - m) * inv;
  float acc0 = hp[lane]*wself, acc1 = hp[lane+64]*wself;
  float nh0=0.f, nh1=0.f, na=0.f;
  if (beg < end){
    int sj = col[beg];
    const float* hs = h + ((size_t)sj*H + hh)*C;
    nh0 = hs[lane]; nh1 = hs[lane+64]; na = asrc[sj*H+hh];
  }
  for (int e = beg; e < end; ++e){
    float h0=nh0, h1v=nh1, a=na;
    if (e+1 < end){
      int sj = col[e+1];
      const float* hs = h + ((size_t)sj*H + hh)*C;
      nh0 = hs[lane]; nh1 = hs[lane+64]; na = asrc[sj*H+hh];
    }
    float wgt = expf(lrelu02(a + adst_i) - m) * inv;
    acc0 += h0*wgt; acc1 += h1v*wgt;
  }
  float o0 = acc0 + bias[hh*C+lane];
  float o1 = acc1 + bias[hh*C+lane+64];
  out[(size_t)w*C + lane]      = elu1(o0);
  out[(size_t)w*C + lane + 64] = elu1(o1);
}

// ---------------- edge MLP feats: feats[e] = [h[src]*h[dst] (128), attr (16)]
__global__ void feats_kernel(const float* __restrict__ hf, const int* __restrict__ eli,
                             const float* __restrict__ attr, float* __restrict__ feats, int E){
  int lane = threadIdx.x & 63;
  int e = blockIdx.x*4 + (threadIdx.x >> 6);
  if (e >= E) return;
  int s = eli[e], d = eli[E+e];
  const float* hs = hf + (size_t)s*128;
  const float* hd = hf + (size_t)d*128;
  float* ft = feats + (size_t)e*144;
  ft[lane]      = hs[lane]      * hd[lane];
  ft[64+lane]   = hs[64+lane]   * hd[64+lane];
  if (lane < 16) ft[128+lane] = attr[(size_t)e*16 + lane];
}

// ---------------- final 64->2 layer: wave per edge, shuffle reduce
__global__ void mlp2_kernel(const float* __restrict__ hidden, const float* __restrict__ w2,
                            const float* __restrict__ b2, float* __restrict__ out, int E){
  int lane = threadIdx.x & 63;
  int e = blockIdx.x*4 + (threadIdx.x >> 6);
  if (e >= E) return;
  float hv = hidden[(size_t)e*64 + lane];
  float p0 = hv * w2[lane*2+0];
  float p1 = hv * w2[lane*2+1];
  p0 = wave_reduce_sum(p0);
  p1 = wave_reduce_sum(p1);
  if (lane==0){
    out[(size_t)e*2+0] = p0 + b2[0];
    out[(size_t)e*2+1] = p1 + b2[1];
  }
}

extern "C" void kernel_launch(void* const* d_in, const int* in_sizes, int n_in,
                              void* d_out, int out_size, void* d_ws, size_t ws_size,
                              hipStream_t stream){
  const float* x    = (const float*)d_in[0];
  const int*   ei   = (const int*)d_in[1];
  // d_in[2] = edge_attr (unused by reference forward)
  const int*   eli  = (const int*)d_in[3];
  const float* attr = (const float*)d_in[4];
  const float* W1   = (const float*)d_in[5];
  const float* as1  = (const float*)d_in[6];
  const float* ad1  = (const float*)d_in[7];
  const float* b1   = (const float*)d_in[8];
  const float* W2   = (const float*)d_in[9];
  const float* as2  = (const float*)d_in[10];
  const float* ad2  = (const float*)d_in[11];
  const float* b2   = (const float*)d_in[12];
  const float* mw1  = (const float*)d_in[13];
  const float* mb1  = (const float*)d_in[14];
  const float* mw2  = (const float*)d_in[15];
  const float* mb2  = (const float*)d_in[16];
  float* out = (float*)d_out;

  const int N  = in_sizes[0]/128;   // 10000
  const int E  = in_sizes[1]/2;     // 160000
  const int EL = in_sizes[3]/2;     // 100000
  const int FIN = 128, H1 = 4, C = 128;

  // ---- workspace layout (floats). feats/hidden overlay the dead h1/out1/h2 chain.
  float* ws = (float*)d_ws;
  size_t off = 0;
  float* out2 = ws + off; off += (size_t)N*C;
  size_t h1_off = off;
  float* h1   = ws + off; off += (size_t)N*H1*C;
  float* out1 = ws + off; off += (size_t)N*H1*C;
  float* h2   = ws + off; off += (size_t)N*C;
  size_t chain_end = off;
  float* feats  = ws + h1_off;
  float* hidden = feats + (size_t)EL*144;
  size_t mlp_end = h1_off + (size_t)EL*144 + (size_t)EL*64;
  off = (chain_end > mlp_end) ? chain_end : mlp_end;
  float* asrc1 = ws + off; off += (size_t)N*H1;
  float* adst1 = ws + off; off += (size_t)N*H1;
  float* asrc2 = ws + off; off += (size_t)N;
  float* adst2 = ws + off; off += (size_t)N;
  int* cnt = (int*)(ws + off); off += (size_t)N;
  int* rp  = (int*)(ws + off); off += (size_t)N+1;
  int* fl  = (int*)(ws + off); off += (size_t)N;
  int* col = (int*)(ws + off); off += (size_t)E;

  // ---- CSR build (shared by both GAT layers)
  hipMemsetAsync(cnt, 0, (size_t)N*sizeof(int), stream);
  hipMemsetAsync(fl,  0, (size_t)N*sizeof(int), stream);
  hist_kernel<<<(E+255)/256, 256, 0, stream>>>(ei, cnt, E);
  scan_kernel<<<1, 1024, 0, stream>>>(cnt, rp, N);
  fill_kernel<<<(E+255)/256, 256, 0, stream>>>(ei, rp, fl, col, E);

  // ---- GAT layer 1 (H=4, C=128)
  gemm_kernel<0><<<dim3((H1*C)/64, (N+63)/64), 256, 0, stream>>>(x, W1, nullptr, h1, N, H1*C, FIN);
  attn_kernel<4><<<(N*H1+3)/4, 256, 0, stream>>>(h1, as1, ad1, asrc1, adst1, N);
  agg_kernel<4><<<(N*H1+3)/4, 256, 0, stream>>>(h1, asrc1, adst1, b1, rp, col, out1, N);

  // ---- GAT layer 2 (H=1, C=128)
  gemm_kernel<0><<<dim3(C/64, (N+63)/64), 256, 0, stream>>>(out1, W2, nullptr, h2, N, C, H1*C);
  attn_kernel<1><<<(N+3)/4, 256, 0, stream>>>(h2, as2, ad2, asrc2, adst2, N);
  agg_kernel<1><<<(N+3)/4, 256, 0, stream>>>(h2, asrc2, adst2, b2, rp, col, out2, N);

  // ---- edge MLP
  feats_kernel<<<(EL+3)/4, 256, 0, stream>>>(out2, eli, attr, feats, EL);
  gemm_kernel<1><<<dim3(1, (EL+63)/64), 256, 0, stream>>>(feats, mw1, mb1, hidden, EL, 64, 144);
  mlp2_kernel<<<(EL+3)/4, 256, 0, stream>>>(hidden, mw2, mb2, out, EL);
}

// Round 2
// 253.676 us; speedup vs baseline: 1.5777x; 1.5777x over previous
//
#include <hip/hip_runtime.h>
#include <hip/hip_bf16.h>
#include <cstdint>

typedef __attribute__((ext_vector_type(8))) short bf16x8;
typedef __attribute__((ext_vector_type(4))) float f32x4;

__device__ __forceinline__ float lrelu02(float x){ return x > 0.f ? x : 0.2f*x; }
__device__ __forceinline__ float elu1(float x){ return x > 0.f ? x : expm1f(x); }
__device__ __forceinline__ unsigned short bf16_rne(float f){
  unsigned int u = __float_as_uint(f);
  u += 0x7FFFu + ((u >> 16) & 1u);
  return (unsigned short)(u >> 16);
}

__device__ __forceinline__ float wave_reduce_sum(float v){
  #pragma unroll
  for (int o = 32; o >= 1; o >>= 1) v += __shfl_xor(v, o, 64);
  return v;
}
__device__ __forceinline__ float wave_reduce_max(float v){
  #pragma unroll
  for (int o = 32; o >= 1; o >>= 1) v = fmaxf(v, __shfl_xor(v, o, 64));
  return v;
}

// ---------------- CSR build ----------------
__global__ void hist_kernel(const int* __restrict__ ei, int* __restrict__ cnt, int E){
  int e = blockIdx.x*blockDim.x + threadIdx.x;
  if (e < E) atomicAdd(&cnt[ei[E + e]], 1);
}

__global__ void scan_kernel(const int* __restrict__ cnt, int* __restrict__ rp, int N){
  __shared__ int part[1024];
  const int PER = 16;
  int t = threadIdx.x;
  int base = t*PER;
  int local[PER]; int s = 0;
  #pragma unroll
  for (int i=0;i<PER;i++){ int idx=base+i; int v = (idx<N)? cnt[idx] : 0; local[i]=s; s+=v; }
  part[t]=s; __syncthreads();
  for (int off=1; off<1024; off<<=1){
    int v = (t>=off)? part[t-off] : 0;
    __syncthreads();
    part[t] += v;
    __syncthreads();
  }
  int ex = (t>0)? part[t-1] : 0;
  #pragma unroll
  for (int i=0;i<PER;i++){ int idx=base+i; if (idx<N) rp[idx] = ex + local[i]; }
  if (t==0) rp[N] = part[1023];
}

__global__ void fill_kernel(const int* __restrict__ ei, const int* __restrict__ rp,
                            int* __restrict__ fl, int* __restrict__ col, int E){
  int e = blockIdx.x*blockDim.x + threadIdx.x;
  if (e >= E) return;
  int d = ei[E+e];
  int pos = rp[d] + atomicAdd(&fl[d], 1);
  col[pos] = ei[e];
}

// ---------------- conversions ----------------
__global__ void f2b_kernel(const float* __restrict__ in, unsigned short* __restrict__ out, int n){
  int i = (blockIdx.x*256 + threadIdx.x)*4;
  if (i >= n) return;
  float4 v = *(const float4*)(in + i);
  out[i+0] = bf16_rne(v.x); out[i+1] = bf16_rne(v.y);
  out[i+2] = bf16_rne(v.z); out[i+3] = bf16_rne(v.w);
}

// W [K][N] f32 -> Wt [N][Kpad] bf16 (zero pad k>=K)
__global__ void wtrans_kernel(const float* __restrict__ W, unsigned short* __restrict__ Wt,
                              int K, int N, int Kpad){
  int idx = blockIdx.x*256 + threadIdx.x;
  if (idx >= N*Kpad) return;
  int n = idx / Kpad, k = idx % Kpad;
  Wt[idx] = (k < K) ? bf16_rne(W[(size_t)k*N + n]) : (unsigned short)0;
}

// ---------------- MFMA bf16 GEMM: C = A[M,K] @ Bt[N,K]^T  (f32 out) ----------
// BM=128 fixed, 4 waves as 2x2; wave tile 64 x (BN/2); 16x16x32 MFMA.
template<int BN, int SPLITK, int RELU, int WB>
__global__ __launch_bounds__(256) void mgemm_kernel(
    const unsigned short* __restrict__ A,  // [M][K] bf16
    const unsigned short* __restrict__ Bt, // [N][K] bf16
    const float* __restrict__ bias,
    float* __restrict__ C,                 // [SPLITK][M][N]
    int M, int N, int K){
  const int BM = 128, BK = 32, LDP = BK + 8;   // padded bf16 stride (80 B, 16B-aligned)
  const int NF = BN/32;                        // frags per wave in N
  __shared__ unsigned short As[BM*LDP];
  __shared__ unsigned short Bs[BN*LDP];
  int tid = threadIdx.x;
  int lane = tid & 63, wid = tid >> 6;
  int wr = wid >> 1, wc = wid & 1;
  int row0 = blockIdx.y*BM, col0 = blockIdx.x*BN;
  int kchunk = K / SPLITK;
  int k0base = blockIdx.z * kchunk;
  f32x4 acc[4][NF];
  #pragma unroll
  for (int m=0;m<4;m++)
    #pragma unroll
    for (int n=0;n<NF;n++) acc[m][n] = (f32x4){0.f,0.f,0.f,0.f};

  for (int kt = 0; kt < kchunk; kt += BK){
    int k0 = k0base + kt;
    // stage A: 128 rows x 4 chunks(16B) -> 2 per thread
    #pragma unroll
    for (int i=0;i<(BM*4)/256;i++){
      int li = i*256 + tid;
      int r = li >> 2, q = li & 3;
      int gr = row0 + r;
      uint4 v = make_uint4(0u,0u,0u,0u);
      if (gr < M) v = *(const uint4*)(A + (size_t)gr*K + k0 + q*8);
      *(uint4*)(&As[r*LDP + q*8]) = v;
    }
    // stage Bt: BN rows x 4 chunks
    #pragma unroll
    for (int i=0;i<(BN*4)/256;i++){
      int li = i*256 + tid;
      int r = li >> 2, q = li & 3;
      int gn = col0 + r;
      uint4 v = make_uint4(0u,0u,0u,0u);
      if (gn < N) v = *(const uint4*)(Bt + (size_t)gn*K + k0 + q*8);
      *(uint4*)(&Bs[r*LDP + q*8]) = v;
    }
    __syncthreads();
    int kq = (lane >> 4) * 8;
    bf16x8 af[4], bfr[NF];
    #pragma unroll
    for (int m=0;m<4;m++)
      af[m] = *(const bf16x8*)(&As[(wr*64 + m*16 + (lane&15))*LDP + kq]);
    #pragma unroll
    for (int n=0;n<NF;n++)
      bfr[n] = *(const bf16x8*)(&Bs[(wc*(BN/2) + n*16 + (lane&15))*LDP + kq]);
    #pragma unroll
    for (int m=0;m<4;m++)
      #pragma unroll
      for (int n=0;n<NF;n++)
        acc[m][n] = __builtin_amdgcn_mfma_f32_16x16x32_bf16(af[m], bfr[n], acc[m][n], 0, 0, 0);
    __syncthreads();
  }
  // epilogue: C/D layout col=lane&15, row=(lane>>4)*4+reg (verified)
  float* Cb = C + (size_t)blockIdx.z * M * N;
  #pragma unroll
  for (int m=0;m<4;m++){
    #pragma unroll
    for (int j=0;j<4;j++){
      int r = row0 + wr*64 + m*16 + (lane>>4)*4 + j;
      if (r >= M) continue;
      #pragma unroll
      for (int n=0;n<NF;n++){
        int c = col0 + wc*(BN/2) + n*16 + (lane&15);
        float v = acc[m][n][j];
        if (WB) v += bias[c];
        if (RELU) v = fmaxf(v, 0.f);
        Cb[(size_t)r*N + c] = v;
      }
    }
  }
}

__global__ void reduce4_kernel(const float4* __restrict__ p, float4* __restrict__ o, int n4, int s4){
  int i = blockIdx.x*256 + threadIdx.x;
  if (i >= n4) return;
  float4 a = p[i], b = p[i+s4], c = p[i+2*s4], d = p[i+3*s4];
  o[i] = make_float4(a.x+b.x+c.x+d.x, a.y+b.y+c.y+d.y, a.z+b.z+c.z+d.z, a.w+b.w+c.w+d.w);
}

// ---------------- attention coefficients: one wave per (node, head), C=128
template<int H>
__global__ void attn_kernel(const float* __restrict__ h,
                            const float* __restrict__ att_src,
                            const float* __restrict__ att_dst,
                            float* __restrict__ asrc, float* __restrict__ adst, int N){
  const int C = 128;
  int lane = threadIdx.x & 63;
  int w = blockIdx.x*4 + (threadIdx.x >> 6);
  if (w >= N*H) return;
  int hh = w % H;
  const float* hp = h + (size_t)w*C;
  float s = hp[lane]*att_src[hh*C+lane] + hp[lane+64]*att_src[hh*C+lane+64];
  float d = hp[lane]*att_dst[hh*C+lane] + hp[lane+64]*att_dst[hh*C+lane+64];
  s = wave_reduce_sum(s); d = wave_reduce_sum(d);
  if (lane==0){ asrc[w]=s; adst[w]=d; }
}

// ---------------- GAT aggregation: one wave per (node, head), C=128
template<int H, int OUTB>
__global__ void agg_kernel(const float* __restrict__ h,
                           const float* __restrict__ asrc,
                           const float* __restrict__ adst,
                           const float* __restrict__ bias,
                           const int* __restrict__ rp,
                           const int* __restrict__ col,
                           void* __restrict__ outv, int N){
  const int C = 128;
  int lane = threadIdx.x & 63;
  int w = blockIdx.x*4 + (threadIdx.x >> 6);
  if (w >= N*H) return;
  int n = w / H, hh = w % H;
  int beg = rp[n], end = rp[n+1];
  float adst_i = adst[w];
  float s_self = lrelu02(asrc[w] + adst_i);
  float m = s_self;
  for (int e = beg+lane; e < end; e += 64)
    m = fmaxf(m, lrelu02(asrc[col[e]*H + hh] + adst_i));
  m = wave_reduce_max(m);
  float ssum = (lane==0)? expf(s_self - m) : 0.f;
  for (int e = beg+lane; e < end; e += 64)
    ssum += expf(lrelu02(asrc[col[e]*H + hh] + adst_i) - m);
  ssum = wave_reduce_sum(ssum);
  float inv = 1.f / fmaxf(ssum, 1e-16f);
  const float* hp = h + (size_t)w*C;
  float wself = expf(s_self - m) * inv;
  float acc0 = hp[lane]*wself, acc1 = hp[lane+64]*wself;
  float nh0=0.f, nh1=0.f, na=0.f;
  if (beg < end){
    int sj = col[beg];
    const float* hs = h + ((size_t)sj*H + hh)*C;
    nh0 = hs[lane]; nh1 = hs[lane+64]; na = asrc[sj*H+hh];
  }
  for (int e = beg; e < end; ++e){
    float h0=nh0, h1v=nh1, a=na;
    if (e+1 < end){
      int sj = col[e+1];
      const float* hs = h + ((size_t)sj*H + hh)*C;
      nh0 = hs[lane]; nh1 = hs[lane+64]; na = asrc[sj*H+hh];
    }
    float wgt = expf(lrelu02(a + adst_i) - m) * inv;
    acc0 += h0*wgt; acc1 += h1v*wgt;
  }
  float o0 = elu1(acc0 + bias[hh*C+lane]);
  float o1 = elu1(acc1 + bias[hh*C+lane+64]);
  if (OUTB){
    unsigned short* o = (unsigned short*)outv;
    o[(size_t)w*C + lane]      = bf16_rne(o0);
    o[(size_t)w*C + lane + 64] = bf16_rne(o1);
  } else {
    float* o = (float*)outv;
    o[(size_t)w*C + lane]      = o0;
    o[(size_t)w*C + lane + 64] = o1;
  }
}

// ---------------- edge MLP feats (bf16, K padded to 160) ----------------
__global__ void feats_kernel(const float* __restrict__ hf, const int* __restrict__ eli,
                             const float* __restrict__ attr, unsigned short* __restrict__ feats, int E){
  int lane = threadIdx.x & 63;
  int e = blockIdx.x*4 + (threadIdx.x >> 6);
  if (e >= E) return;
  int s = eli[e], d = eli[E+e];
  const float* hs = hf + (size_t)s*128;
  const float* hd = hf + (size_t)d*128;
  unsigned short* ft = feats + (size_t)e*160;
  ft[lane]      = bf16_rne(hs[lane]      * hd[lane]);
  ft[64+lane]   = bf16_rne(hs[64+lane]   * hd[64+lane]);
  if (lane < 16)      ft[128+lane] = bf16_rne(attr[(size_t)e*16 + lane]);
  else if (lane < 32) ft[128+lane] = 0;
}

// ---------------- final 64->2 layer ----------------
__global__ void mlp2_kernel(const float* __restrict__ hidden, const float* __restrict__ w2,
                            const float* __restrict__ b2, float* __restrict__ out, int E){
  int lane = threadIdx.x & 63;
  int e = blockIdx.x*4 + (threadIdx.x >> 6);
  if (e >= E) return;
  float hv = hidden[(size_t)e*64 + lane];
  float p0 = hv * w2[lane*2+0];
  float p1 = hv * w2[lane*2+1];
  p0 = wave_reduce_sum(p0);
  p1 = wave_reduce_sum(p1);
  if (lane==0){
    out[(size_t)e*2+0] = p0 + b2[0];
    out[(size_t)e*2+1] = p1 + b2[1];
  }
}

extern "C" void kernel_launch(void* const* d_in, const int* in_sizes, int n_in,
                              void* d_out, int out_size, void* d_ws, size_t ws_size,
                              hipStream_t stream){
  const float* x    = (const float*)d_in[0];
  const int*   ei   = (const int*)d_in[1];
  const int*   eli  = (const int*)d_in[3];
  const float* attr = (const float*)d_in[4];
  const float* W1   = (const float*)d_in[5];
  const float* as1  = (const float*)d_in[6];
  const float* ad1  = (const float*)d_in[7];
  const float* b1   = (const float*)d_in[8];
  const float* W2   = (const float*)d_in[9];
  const float* as2  = (const float*)d_in[10];
  const float* ad2  = (const float*)d_in[11];
  const float* b2   = (const float*)d_in[12];
  const float* mw1  = (const float*)d_in[13];
  const float* mb1  = (const float*)d_in[14];
  const float* mw2  = (const float*)d_in[15];
  const float* mb2  = (const float*)d_in[16];
  float* out = (float*)d_out;

  const int N  = in_sizes[0]/128;   // 10000
  const int E  = in_sizes[1]/2;     // 160000
  const int EL = in_sizes[3]/2;     // 100000
  const int H1 = 4, C = 128;
  const int K1 = 128, N1 = 512;     // gemm1
  const int K2 = 512, N2 = 128;     // gemm2 (splitK=4)
  const int K3 = 160, N3 = 64;      // mlp gemm (padded K)

  // ---- workspace layout (bytes) ----
  char* ws = (char*)d_ws;
  size_t off = 0;
  float* out2 = (float*)(ws + off); off += (size_t)N*C*4;                       // 5.12 MB
  // regionA: xb + h1 + out1b  (33.28 MB)  overlaid later by featsb (32 MB)
  size_t regA = off;
  unsigned short* xb    = (unsigned short*)(ws + off); off += (size_t)N*K1*2;   // 2.56 MB
  float*          h1    = (float*)(ws + off);          off += (size_t)N*N1*4;   // 20.48 MB
  unsigned short* out1b = (unsigned short*)(ws + off); off += (size_t)N*N1*2;   // 10.24 MB
  unsigned short* featsb = (unsigned short*)(ws + regA);                        // [EL][160]
  // regionB: partials + h2 (25.6 MB) overlaid later by hidden (25.6 MB)
  size_t regB = off;
  float* part = (float*)(ws + off); off += (size_t)4*N*N2*4;                    // 20.48 MB
  float* h2   = (float*)(ws + off); off += (size_t)N*N2*4;                      // 5.12 MB
  float* hidden = (float*)(ws + regB);                                          // [EL][64]
  // small stuff
  unsigned short* W1t  = (unsigned short*)(ws + off); off += (size_t)N1*K1*2;
  unsigned short* W2t  = (unsigned short*)(ws + off); off += (size_t)N2*K2*2;
  unsigned short* mw1t = (unsigned short*)(ws + off); off += (size_t)N3*K3*2;
  float* asrc1 = (float*)(ws + off); off += (size_t)N*H1*4;
  float* adst1 = (float*)(ws + off); off += (size_t)N*H1*4;
  float* asrc2 = (float*)(ws + off); off += (size_t)N*4;
  float* adst2 = (float*)(ws + off); off += (size_t)N*4;
  int* cnt = (int*)(ws + off); off += (size_t)N*4;
  int* rp  = (int*)(ws + off); off += (size_t)(N+1)*4;
  int* fl  = (int*)(ws + off); off += (size_t)N*4;
  int* col = (int*)(ws + off); off += (size_t)E*4;

  // ---- CSR build ----
  hipMemsetAsync(cnt, 0, (size_t)N*4, stream);
  hipMemsetAsync(fl,  0, (size_t)N*4, stream);
  hist_kernel<<<(E+255)/256, 256, 0, stream>>>(ei, cnt, E);
  scan_kernel<<<1, 1024, 0, stream>>>(cnt, rp, N);
  fill_kernel<<<(E+255)/256, 256, 0, stream>>>(ei, rp, fl, col, E);

  // ---- conversions ----
  f2b_kernel<<<(N*K1/4+255)/256, 256, 0, stream>>>(x, xb, N*K1);
  wtrans_kernel<<<(N1*K1+255)/256, 256, 0, stream>>>(W1, W1t, K1, N1, K1);
  wtrans_kernel<<<(N2*K2+255)/256, 256, 0, stream>>>(W2, W2t, K2, N2, K2);
  wtrans_kernel<<<(N3*K3+255)/256, 256, 0, stream>>>(mw1, mw1t, 144, N3, K3);

  // ---- GAT layer 1 ----
  mgemm_kernel<128,1,0,0><<<dim3(N1/128, (N+127)/128, 1), 256, 0, stream>>>(
      xb, W1t, nullptr, h1, N, N1, K1);
  attn_kernel<4><<<(N*H1+3)/4, 256, 0, stream>>>(h1, as1, ad1, asrc1, adst1, N);
  agg_kernel<4,1><<<(N*H1+3)/4, 256, 0, stream>>>(h1, asrc1, adst1, b1, rp, col, out1b, N);

  // ---- GAT layer 2 (splitK=4) ----
  mgemm_kernel<128,4,0,0><<<dim3(1, (N+127)/128, 4), 256, 0, stream>>>(
      out1b, W2t, nullptr, part, N, N2, K2);
  reduce4_kernel<<<(N*N2/4+255)/256, 256, 0, stream>>>(
      (const float4*)part, (float4*)h2, N*N2/4, N*N2/4);
  attn_kernel<1><<<(N+3)/4, 256, 0, stream>>>(h2, as2, ad2, asrc2, adst2, N);
  agg_kernel<1,0><<<(N+3)/4, 256, 0, stream>>>(h2, asrc2, adst2, b2, rp, col, out2, N);

  // ---- edge MLP ----
  feats_kernel<<<(EL+3)/4, 256, 0, stream>>>(out2, eli, attr, featsb, EL);
  mgemm_kernel<64,1,1,1><<<dim3(1, (EL+127)/128, 1), 256, 0, stream>>>(
      featsb, mw1t, mb1, hidden, EL, N3, K3);
  mlp2_kernel<<<(EL+3)/4, 256, 0, stream>>>(hidden, mw2, mb2, out, EL);
}

// Round 4
// 209.335 us; speedup vs baseline: 1.9119x; 1.2118x over previous
//
#include <hip/hip_runtime.h>
#include <hip/hip_bf16.h>
#include <cstdint>

typedef __attribute__((ext_vector_type(8))) short bf16x8;
typedef __attribute__((ext_vector_type(4))) float f32x4;

__device__ __forceinline__ float lrelu02(float x){ return x > 0.f ? x : 0.2f*x; }
__device__ __forceinline__ float elu1(float x){ return x > 0.f ? x : __expf(x)-1.f; }
__device__ __forceinline__ unsigned short bf16_rne(float f){
  unsigned int u = __float_as_uint(f);
  u += 0x7FFFu + ((u >> 16) & 1u);
  return (unsigned short)(u >> 16);
}

__device__ __forceinline__ float wave_reduce_sum(float v){
  #pragma unroll
  for (int o = 32; o >= 1; o >>= 1) v += __shfl_xor(v, o, 64);
  return v;
}
__device__ __forceinline__ float wave_reduce_max(float v){
  #pragma unroll
  for (int o = 32; o >= 1; o >>= 1) v = fmaxf(v, __shfl_xor(v, o, 64));
  return v;
}

// ---------------- CSR build ----------------
__global__ void hist_kernel(const int* __restrict__ ei, int* __restrict__ cnt, int E){
  int e = blockIdx.x*blockDim.x + threadIdx.x;
  if (e < E) atomicAdd(&cnt[ei[E + e]], 1);
}

__global__ void scan_kernel(const int* __restrict__ cnt, int* __restrict__ rp, int N){
  __shared__ int part[1024];
  const int PER = 16;
  int t = threadIdx.x;
  int base = t*PER;
  int local[PER]; int s = 0;
  #pragma unroll
  for (int i=0;i<PER;i++){ int idx=base+i; int v = (idx<N)? cnt[idx] : 0; local[i]=s; s+=v; }
  part[t]=s; __syncthreads();
  for (int off=1; off<1024; off<<=1){
    int v = (t>=off)? part[t-off] : 0;
    __syncthreads();
    part[t] += v;
    __syncthreads();
  }
  int ex = (t>0)? part[t-1] : 0;
  #pragma unroll
  for (int i=0;i<PER;i++){ int idx=base+i; if (idx<N) rp[idx] = ex + local[i]; }
  if (t==0) rp[N] = part[1023];
}

__global__ void fill_kernel(const int* __restrict__ ei, const int* __restrict__ rp,
                            int* __restrict__ fl, int* __restrict__ col, int E){
  int e = blockIdx.x*blockDim.x + threadIdx.x;
  if (e >= E) return;
  int d = ei[E+e];
  int pos = rp[d] + atomicAdd(&fl[d], 1);
  col[pos] = ei[e];
}

// ---------------- conversions ----------------
__global__ void f2b_kernel(const float* __restrict__ in, unsigned short* __restrict__ out, int n){
  int i = (blockIdx.x*256 + threadIdx.x)*4;
  if (i >= n) return;
  float4 v = *(const float4*)(in + i);
  out[i+0] = bf16_rne(v.x); out[i+1] = bf16_rne(v.y);
  out[i+2] = bf16_rne(v.z); out[i+3] = bf16_rne(v.w);
}

// W [K][N] f32 -> Wt [N][Kpad] bf16 (zero pad k>=K)
__global__ void wtrans_kernel(const float* __restrict__ W, unsigned short* __restrict__ Wt,
                              int K, int N, int Kpad){
  int idx = blockIdx.x*256 + threadIdx.x;
  if (idx >= N*Kpad) return;
  int n = idx / Kpad, k = idx % Kpad;
  Wt[idx] = (k < K) ? bf16_rne(W[(size_t)k*N + n]) : (unsigned short)0;
}

// ---------------- MFMA bf16 GEMM: C = A[M,K] @ Bt[N,K]^T  (f32 out) ----------
template<int BN, int SPLITK, int RELU, int WB>
__global__ __launch_bounds__(256) void mgemm_kernel(
    const unsigned short* __restrict__ A,  // [M][K] bf16
    const unsigned short* __restrict__ Bt, // [N][K] bf16
    const float* __restrict__ bias,
    float* __restrict__ C,                 // [SPLITK][M][N]
    int M, int N, int K){
  const int BM = 128, BK = 32, LDP = BK + 8;
  const int NF = BN/32;
  __shared__ unsigned short As[BM*LDP];
  __shared__ unsigned short Bs[BN*LDP];
  int tid = threadIdx.x;
  int lane = tid & 63, wid = tid >> 6;
  int wr = wid >> 1, wc = wid & 1;
  int row0 = blockIdx.y*BM, col0 = blockIdx.x*BN;
  int kchunk = K / SPLITK;
  int k0base = blockIdx.z * kchunk;
  f32x4 acc[4][NF];
  #pragma unroll
  for (int m=0;m<4;m++)
    #pragma unroll
    for (int n=0;n<NF;n++) acc[m][n] = (f32x4){0.f,0.f,0.f,0.f};

  for (int kt = 0; kt < kchunk; kt += BK){
    int k0 = k0base + kt;
    #pragma unroll
    for (int i=0;i<(BM*4)/256;i++){
      int li = i*256 + tid;
      int r = li >> 2, q = li & 3;
      int gr = row0 + r;
      uint4 v = make_uint4(0u,0u,0u,0u);
      if (gr < M) v = *(const uint4*)(A + (size_t)gr*K + k0 + q*8);
      *(uint4*)(&As[r*LDP + q*8]) = v;
    }
    #pragma unroll
    for (int i=0;i<(BN*4)/256;i++){
      int li = i*256 + tid;
      int r = li >> 2, q = li & 3;
      int gn = col0 + r;
      uint4 v = make_uint4(0u,0u,0u,0u);
      if (gn < N) v = *(const uint4*)(Bt + (size_t)gn*K + k0 + q*8);
      *(uint4*)(&Bs[r*LDP + q*8]) = v;
    }
    __syncthreads();
    int kq = (lane >> 4) * 8;
    bf16x8 af[4], bfr[NF];
    #pragma unroll
    for (int m=0;m<4;m++)
      af[m] = *(const bf16x8*)(&As[(wr*64 + m*16 + (lane&15))*LDP + kq]);
    #pragma unroll
    for (int n=0;n<NF;n++)
      bfr[n] = *(const bf16x8*)(&Bs[(wc*(BN/2) + n*16 + (lane&15))*LDP + kq]);
    #pragma unroll
    for (int m=0;m<4;m++)
      #pragma unroll
      for (int n=0;n<NF;n++)
        acc[m][n] = __builtin_amdgcn_mfma_f32_16x16x32_bf16(af[m], bfr[n], acc[m][n], 0, 0, 0);
    __syncthreads();
  }
  float* Cb = C + (size_t)blockIdx.z * M * N;
  #pragma unroll
  for (int m=0;m<4;m++){
    #pragma unroll
    for (int j=0;j<4;j++){
      int r = row0 + wr*64 + m*16 + (lane>>4)*4 + j;
      if (r >= M) continue;
      #pragma unroll
      for (int n=0;n<NF;n++){
        int c = col0 + wc*(BN/2) + n*16 + (lane&15);
        float v = acc[m][n][j];
        if (WB) v += bias[c];
        if (RELU) v = fmaxf(v, 0.f);
        Cb[(size_t)r*N + c] = v;
      }
    }
  }
}

__global__ void reduce4_kernel(const float4* __restrict__ p, float4* __restrict__ o, int n4, int s4){
  int i = blockIdx.x*256 + threadIdx.x;
  if (i >= n4) return;
  float4 a = p[i], b = p[i+s4], c = p[i+2*s4], d = p[i+3*s4];
  o[i] = make_float4(a.x+b.x+c.x+d.x, a.y+b.y+c.y+d.y, a.z+b.z+c.z+d.z, a.w+b.w+c.w+d.w);
}

// ---------------- attention coefficients: one wave per (node, head), C=128
template<int H>
__global__ void attn_kernel(const float* __restrict__ h,
                            const float* __restrict__ att_src,
                            const float* __restrict__ att_dst,
                            float* __restrict__ asrc, float* __restrict__ adst, int N){
  const int C = 128;
  int lane = threadIdx.x & 63;
  int w = blockIdx.x*4 + (threadIdx.x >> 6);
  if (w >= N*H) return;
  int hh = w % H;
  const float* hp = h + (size_t)w*C;
  float s = hp[lane]*att_src[hh*C+lane] + hp[lane+64]*att_src[hh*C+lane+64];
  float d = hp[lane]*att_dst[hh*C+lane] + hp[lane+64]*att_dst[hh*C+lane+64];
  s = wave_reduce_sum(s); d = wave_reduce_sum(d);
  if (lane==0){ asrc[w]=s; adst[w]=d; }
}

// ---------------- GAT aggregation: one wave per (node, head), C=128
// pass 3: round-2 arithmetic, software-pipelined 4 edges wide (8 gathers in flight)
template<int H, int OUTB>
__global__ void agg_kernel(const float* __restrict__ h,
                           const float* __restrict__ asrc,
                           const float* __restrict__ adst,
                           const float* __restrict__ bias,
                           const int* __restrict__ rp,
                           const int* __restrict__ col,
                           void* __restrict__ outv, int N){
  const int C = 128;
  int lane = threadIdx.x & 63;
  int w = blockIdx.x*4 + (threadIdx.x >> 6);
  if (w >= N*H) return;
  int n = w / H, hh = w % H;
  int beg = rp[n], end = rp[n+1];
  float adst_i = adst[w];
  float s_self = lrelu02(asrc[w] + adst_i);
  float m = s_self;
  for (int e = beg+lane; e < end; e += 64)
    m = fmaxf(m, lrelu02(asrc[col[e]*H + hh] + adst_i));
  m = wave_reduce_max(m);
  float ssum = (lane==0)? __expf(s_self - m) : 0.f;
  for (int e = beg+lane; e < end; e += 64)
    ssum += __expf(lrelu02(asrc[col[e]*H + hh] + adst_i) - m);
  ssum = wave_reduce_sum(ssum);
  float inv = 1.f / fmaxf(ssum, 1e-16f);
  const float* hp = h + (size_t)w*C;
  float wself = __expf(s_self - m) * inv;
  float acc0 = hp[lane]*wself, acc1 = hp[lane+64]*wself;

  int e = beg;
  for (; e + 4 <= end; e += 4){
    int r0 = col[e]*H+hh, r1 = col[e+1]*H+hh, r2 = col[e+2]*H+hh, r3 = col[e+3]*H+hh;
    const float* q0 = h + (size_t)r0*C;
    const float* q1 = h + (size_t)r1*C;
    const float* q2 = h + (size_t)r2*C;
    const float* q3 = h + (size_t)r3*C;
    float a0 = q0[lane],    a1 = q1[lane],    a2 = q2[lane],    a3 = q3[lane];
    float c0 = q0[lane+64], c1 = q1[lane+64], c2 = q2[lane+64], c3 = q3[lane+64];
    float s0 = asrc[r0], s1 = asrc[r1], s2 = asrc[r2], s3 = asrc[r3];
    float w0 = __expf(lrelu02(s0 + adst_i) - m) * inv;
    float w1 = __expf(lrelu02(s1 + adst_i) - m) * inv;
    float w2 = __expf(lrelu02(s2 + adst_i) - m) * inv;
    float w3 = __expf(lrelu02(s3 + adst_i) - m) * inv;
    acc0 += a0*w0; acc1 += c0*w0;
    acc0 += a1*w1; acc1 += c1*w1;
    acc0 += a2*w2; acc1 += c2*w2;
    acc0 += a3*w3; acc1 += c3*w3;
  }
  for (; e < end; ++e){
    int r0 = col[e]*H+hh;
    const float* q0 = h + (size_t)r0*C;
    float a0 = q0[lane], c0 = q0[lane+64];
    float w0 = __expf(lrelu02(asrc[r0] + adst_i) - m) * inv;
    acc0 += a0*w0; acc1 += c0*w0;
  }
  float o0 = elu1(acc0 + bias[hh*C+lane]);
  float o1 = elu1(acc1 + bias[hh*C+lane+64]);
  if (OUTB){
    unsigned short* o = (unsigned short*)outv;
    o[(size_t)w*C + lane]      = bf16_rne(o0);
    o[(size_t)w*C + lane + 64] = bf16_rne(o1);
  } else {
    float* o = (float*)outv;
    o[(size_t)w*C + lane]      = o0;
    o[(size_t)w*C + lane + 64] = o1;
  }
}

// ---------------- edge MLP feats (bf16, K padded to 160) ----------------
__global__ void feats_kernel(const float* __restrict__ hf, const int* __restrict__ eli,
                             const float* __restrict__ attr, unsigned short* __restrict__ feats, int E){
  int lane = threadIdx.x & 63;
  int e = blockIdx.x*4 + (threadIdx.x >> 6);
  if (e >= E) return;
  int s = eli[e], d = eli[E+e];
  const float* hs = hf + (size_t)s*128;
  const float* hd = hf + (size_t)d*128;
  unsigned short* ft = feats + (size_t)e*160;
  ft[lane]      = bf16_rne(hs[lane]      * hd[lane]);
  ft[64+lane]   = bf16_rne(hs[64+lane]   * hd[64+lane]);
  if (lane < 16)      ft[128+lane] = bf16_rne(attr[(size_t)e*16 + lane]);
  else if (lane < 32) ft[128+lane] = 0;
}

// ---------------- final 64->2 layer ----------------
__global__ void mlp2_kernel(const float* __restrict__ hidden, const float* __restrict__ w2,
                            const float* __restrict__ b2, float* __restrict__ out, int E){
  int lane = threadIdx.x & 63;
  int e = blockIdx.x*4 + (threadIdx.x >> 6);
  if (e >= E) return;
  float hv = hidden[(size_t)e*64 + lane];
  float p0 = hv * w2[lane*2+0];
  float p1 = hv * w2[lane*2+1];
  p0 = wave_reduce_sum(p0);
  p1 = wave_reduce_sum(p1);
  if (lane==0){
    out[(size_t)e*2+0] = p0 + b2[0];
    out[(size_t)e*2+1] = p1 + b2[1];
  }
}

extern "C" void kernel_launch(void* const* d_in, const int* in_sizes, int n_in,
                              void* d_out, int out_size, void* d_ws, size_t ws_size,
                              hipStream_t stream){
  const float* x    = (const float*)d_in[0];
  const int*   ei   = (const int*)d_in[1];
  const int*   eli  = (const int*)d_in[3];
  const float* attr = (const float*)d_in[4];
  const float* W1   = (const float*)d_in[5];
  const float* as1  = (const float*)d_in[6];
  const float* ad1  = (const float*)d_in[7];
  const float* b1   = (const float*)d_in[8];
  const float* W2   = (const float*)d_in[9];
  const float* as2  = (const float*)d_in[10];
  const float* ad2  = (const float*)d_in[11];
  const float* b2   = (const float*)d_in[12];
  const float* mw1  = (const float*)d_in[13];
  const float* mb1  = (const float*)d_in[14];
  const float* mw2  = (const float*)d_in[15];
  const float* mb2  = (const float*)d_in[16];
  float* out = (float*)d_out;

  const int N  = in_sizes[0]/128;   // 10000
  const int E  = in_sizes[1]/2;     // 160000
  const int EL = in_sizes[3]/2;     // 100000
  const int H1 = 4, C = 128;
  const int K1 = 128, N1 = 512;
  const int K2 = 512, N2 = 128;
  const int K3 = 160, N3 = 64;

  // ---- workspace layout (bytes) ----
  char* ws = (char*)d_ws;
  size_t off = 0;
  float* out2 = (float*)(ws + off); off += (size_t)N*C*4;
  size_t regA = off;
  unsigned short* xb    = (unsigned short*)(ws + off); off += (size_t)N*K1*2;
  float*          h1    = (float*)(ws + off);          off += (size_t)N*N1*4;
  unsigned short* out1b = (unsigned short*)(ws + off); off += (size_t)N*N1*2;
  unsigned short* featsb = (unsigned short*)(ws + regA);   // [EL][160] bf16 (32 MB)
  size_t regB = off;
  float* part = (float*)(ws + off); off += (size_t)4*N*N2*4;
  float* h2   = (float*)(ws + off); off += (size_t)N*N2*4;
  float* hidden = (float*)(ws + regB);                     // [EL][64] f32 (25.6 MB)
  unsigned short* W1t  = (unsigned short*)(ws + off); off += (size_t)N1*K1*2;
  unsigned short* W2t  = (unsigned short*)(ws + off); off += (size_t)N2*K2*2;
  unsigned short* mw1t = (unsigned short*)(ws + off); off += (size_t)N3*K3*2;
  float* asrc1 = (float*)(ws + off); off += (size_t)N*H1*4;
  float* adst1 = (float*)(ws + off); off += (size_t)N*H1*4;
  float* asrc2 = (float*)(ws + off); off += (size_t)N*4;
  float* adst2 = (float*)(ws + off); off += (size_t)N*4;
  int* cnt = (int*)(ws + off); off += (size_t)N*4;
  int* rp  = (int*)(ws + off); off += (size_t)(N+1)*4;
  int* fl  = (int*)(ws + off); off += (size_t)N*4;
  int* col = (int*)(ws + off); off += (size_t)E*4;

  // ---- CSR build ----
  hipMemsetAsync(cnt, 0, (size_t)N*4, stream);
  hipMemsetAsync(fl,  0, (size_t)N*4, stream);
  hist_kernel<<<(E+255)/256, 256, 0, stream>>>(ei, cnt, E);
  scan_kernel<<<1, 1024, 0, stream>>>(cnt, rp, N);
  fill_kernel<<<(E+255)/256, 256, 0, stream>>>(ei, rp, fl, col, E);

  // ---- conversions ----
  f2b_kernel<<<(N*K1/4+255)/256, 256, 0, stream>>>(x, xb, N*K1);
  wtrans_kernel<<<(N1*K1+255)/256, 256, 0, stream>>>(W1, W1t, K1, N1, K1);
  wtrans_kernel<<<(N2*K2+255)/256, 256, 0, stream>>>(W2, W2t, K2, N2, K2);
  wtrans_kernel<<<(N3*K3+255)/256, 256, 0, stream>>>(mw1, mw1t, 144, N3, K3);

  // ---- GAT layer 1 ----
  mgemm_kernel<128,1,0,0><<<dim3(N1/128, (N+127)/128, 1), 256, 0, stream>>>(
      xb, W1t, nullptr, h1, N, N1, K1);
  attn_kernel<4><<<(N*H1+3)/4, 256, 0, stream>>>(h1, as1, ad1, asrc1, adst1, N);
  agg_kernel<4,1><<<(N*H1+3)/4, 256, 0, stream>>>(h1, asrc1, adst1, b1, rp, col, out1b, N);

  // ---- GAT layer 2 (splitK=4) ----
  mgemm_kernel<128,4,0,0><<<dim3(1, (N+127)/128, 4), 256, 0, stream>>>(
      out1b, W2t, nullptr, part, N, N2, K2);
  reduce4_kernel<<<(N*N2/4+255)/256, 256, 0, stream>>>(
      (const float4*)part, (float4*)h2, N*N2/4, N*N2/4);
  attn_kernel<1><<<(N+3)/4, 256, 0, stream>>>(h2, as2, ad2, asrc2, adst2, N);
  agg_kernel<1,0><<<(N+3)/4, 256, 0, stream>>>(h2, asrc2, adst2, b2, rp, col, out2, N);

  // ---- edge MLP ----
  feats_kernel<<<(EL+3)/4, 256, 0, stream>>>(out2, eli, attr, featsb, EL);
  mgemm_kernel<64,1,1,1><<<dim3(1, (EL+127)/128, 1), 256, 0, stream>>>(
      featsb, mw1t, mb1, hidden, EL, N3, K3);
  mlp2_kernel<<<(EL+3)/4, 256, 0, stream>>>(hidden, mw2, mb2, out, EL);
}

// Round 5
// 189.158 us; speedup vs baseline: 2.1159x; 1.1067x over previous
//
#include <hip/hip_runtime.h>
#include <hip/hip_bf16.h>
#include <cstdint>

typedef __attribute__((ext_vector_type(8))) short bf16x8;
typedef __attribute__((ext_vector_type(4))) float f32x4;

__device__ __forceinline__ float lrelu02(float x){ return x > 0.f ? x : 0.2f*x; }
__device__ __forceinline__ float elu1(float x){ return x > 0.f ? x : __expf(x)-1.f; }
__device__ __forceinline__ unsigned short bf16_rne(float f){
  unsigned int u = __float_as_uint(f);
  u += 0x7FFFu + ((u >> 16) & 1u);
  return (unsigned short)(u >> 16);
}
__device__ __forceinline__ float b2f(unsigned int hi16){ return __uint_as_float(hi16 << 16); }
__device__ __forceinline__ unsigned int packbf(float a, float b){
  return (unsigned int)bf16_rne(a) | ((unsigned int)bf16_rne(b) << 16);
}

__device__ __forceinline__ float wave_reduce_sum(float v){
  #pragma unroll
  for (int o = 32; o >= 1; o >>= 1) v += __shfl_xor(v, o, 64);
  return v;
}

// ---------------- CSR build ----------------
__global__ void hist_kernel(const int* __restrict__ ei, int* __restrict__ cnt, int E){
  int e = blockIdx.x*blockDim.x + threadIdx.x;
  if (e < E) atomicAdd(&cnt[ei[E + e]], 1);
}

__global__ void scan_kernel(const int* __restrict__ cnt, int* __restrict__ rp, int N){
  __shared__ int part[1024];
  const int PER = 16;
  int t = threadIdx.x;
  int base = t*PER;
  int local[PER]; int s = 0;
  #pragma unroll
  for (int i=0;i<PER;i++){ int idx=base+i; int v = (idx<N)? cnt[idx] : 0; local[i]=s; s+=v; }
  part[t]=s; __syncthreads();
  for (int off=1; off<1024; off<<=1){
    int v = (t>=off)? part[t-off] : 0;
    __syncthreads();
    part[t] += v;
    __syncthreads();
  }
  int ex = (t>0)? part[t-1] : 0;
  #pragma unroll
  for (int i=0;i<PER;i++){ int idx=base+i; if (idx<N) rp[idx] = ex + local[i]; }
  if (t==0) rp[N] = part[1023];
}

__global__ void fill_kernel(const int* __restrict__ ei, const int* __restrict__ rp,
                            int* __restrict__ fl, int* __restrict__ col, int E){
  int e = blockIdx.x*blockDim.x + threadIdx.x;
  if (e >= E) return;
  int d = ei[E+e];
  int pos = rp[d] + atomicAdd(&fl[d], 1);
  col[pos] = ei[e];
}

// ---------------- conversions ----------------
__global__ void f2b_kernel(const float* __restrict__ in, unsigned short* __restrict__ out, int n){
  int i = (blockIdx.x*256 + threadIdx.x)*4;
  if (i >= n) return;
  float4 v = *(const float4*)(in + i);
  out[i+0] = bf16_rne(v.x); out[i+1] = bf16_rne(v.y);
  out[i+2] = bf16_rne(v.z); out[i+3] = bf16_rne(v.w);
}

// W [K][N] f32 -> Wt [N][Kpad] bf16 (zero pad k>=K)
__global__ void wtrans_kernel(const float* __restrict__ W, unsigned short* __restrict__ Wt,
                              int K, int N, int Kpad){
  int idx = blockIdx.x*256 + threadIdx.x;
  if (idx >= N*Kpad) return;
  int n = idx / Kpad, k = idx % Kpad;
  Wt[idx] = (k < K) ? bf16_rne(W[(size_t)k*N + n]) : (unsigned short)0;
}

// ---------------- MFMA bf16 GEMM: C = A[M,K] @ Bt[N,K]^T ----------
// OUTB=1: write bf16 (SPLITK must be 1). OUTB=0: write f32 (+z-sliced for SPLITK).
template<int BN, int SPLITK, int RELU, int WB, int OUTB>
__global__ __launch_bounds__(256) void mgemm_kernel(
    const unsigned short* __restrict__ A,  // [M][K] bf16
    const unsigned short* __restrict__ Bt, // [N][K] bf16
    const float* __restrict__ bias,
    void* __restrict__ C,
    int M, int N, int K){
  const int BM = 128, BK = 32, LDP = BK + 8;
  const int NF = BN/32;
  __shared__ unsigned short As[BM*LDP];
  __shared__ unsigned short Bs[BN*LDP];
  int tid = threadIdx.x;
  int lane = tid & 63, wid = tid >> 6;
  int wr = wid >> 1, wc = wid & 1;
  int row0 = blockIdx.y*BM, col0 = blockIdx.x*BN;
  int kchunk = K / SPLITK;
  int k0base = blockIdx.z * kchunk;
  f32x4 acc[4][NF];
  #pragma unroll
  for (int m=0;m<4;m++)
    #pragma unroll
    for (int n=0;n<NF;n++) acc[m][n] = (f32x4){0.f,0.f,0.f,0.f};

  for (int kt = 0; kt < kchunk; kt += BK){
    int k0 = k0base + kt;
    #pragma unroll
    for (int i=0;i<(BM*4)/256;i++){
      int li = i*256 + tid;
      int r = li >> 2, q = li & 3;
      int gr = row0 + r;
      uint4 v = make_uint4(0u,0u,0u,0u);
      if (gr < M) v = *(const uint4*)(A + (size_t)gr*K + k0 + q*8);
      *(uint4*)(&As[r*LDP + q*8]) = v;
    }
    #pragma unroll
    for (int i=0;i<(BN*4)/256;i++){
      int li = i*256 + tid;
      int r = li >> 2, q = li & 3;
      int gn = col0 + r;
      uint4 v = make_uint4(0u,0u,0u,0u);
      if (gn < N) v = *(const uint4*)(Bt + (size_t)gn*K + k0 + q*8);
      *(uint4*)(&Bs[r*LDP + q*8]) = v;
    }
    __syncthreads();
    int kq = (lane >> 4) * 8;
    bf16x8 af[4], bfr[NF];
    #pragma unroll
    for (int m=0;m<4;m++)
      af[m] = *(const bf16x8*)(&As[(wr*64 + m*16 + (lane&15))*LDP + kq]);
    #pragma unroll
    for (int n=0;n<NF;n++)
      bfr[n] = *(const bf16x8*)(&Bs[(wc*(BN/2) + n*16 + (lane&15))*LDP + kq]);
    #pragma unroll
    for (int m=0;m<4;m++)
      #pragma unroll
      for (int n=0;n<NF;n++)
        acc[m][n] = __builtin_amdgcn_mfma_f32_16x16x32_bf16(af[m], bfr[n], acc[m][n], 0, 0, 0);
    __syncthreads();
  }
  #pragma unroll
  for (int m=0;m<4;m++){
    #pragma unroll
    for (int j=0;j<4;j++){
      int r = row0 + wr*64 + m*16 + (lane>>4)*4 + j;
      if (r >= M) continue;
      #pragma unroll
      for (int n=0;n<NF;n++){
        int c = col0 + wc*(BN/2) + n*16 + (lane&15);
        float v = acc[m][n][j];
        if (WB) v += bias[c];
        if (RELU) v = fmaxf(v, 0.f);
        if (OUTB){
          ((unsigned short*)C)[(size_t)r*N + c] = bf16_rne(v);
        } else {
          float* Cb = (float*)C + (size_t)blockIdx.z * M * N;
          Cb[(size_t)r*N + c] = v;
        }
      }
    }
  }
}

// sum 4 split-K partials -> bf16
__global__ void reduce4b_kernel(const float4* __restrict__ p, uint2* __restrict__ o, int n4, int s4){
  int i = blockIdx.x*256 + threadIdx.x;
  if (i >= n4) return;
  float4 a = p[i], b = p[i+s4], c = p[i+2*s4], d = p[i+3*s4];
  float rx = a.x+b.x+c.x+d.x, ry = a.y+b.y+c.y+d.y;
  float rz = a.z+b.z+c.z+d.z, rw = a.w+b.w+c.w+d.w;
  o[i] = make_uint2(packbf(rx, ry), packbf(rz, rw));
}

// ---------------- attention coefficients (h in bf16): one wave per (node, head)
template<int H>
__global__ void attn_kernel(const unsigned short* __restrict__ h,
                            const float* __restrict__ att_src,
                            const float* __restrict__ att_dst,
                            float* __restrict__ asrc, float* __restrict__ adst, int N){
  const int C = 128;
  int lane = threadIdx.x & 63;
  int w = blockIdx.x*4 + (threadIdx.x >> 6);
  if (w >= N*H) return;
  int hh = w % H;
  const unsigned int* hp = (const unsigned int*)(h + (size_t)w*C);
  unsigned int u = hp[lane];
  float v0 = b2f(u & 0xffffu), v1 = b2f(u >> 16);
  int c0 = 2*lane;
  float s = v0*att_src[hh*C+c0] + v1*att_src[hh*C+c0+1];
  float d = v0*att_dst[hh*C+c0] + v1*att_dst[hh*C+c0+1];
  s = wave_reduce_sum(s); d = wave_reduce_sum(d);
  if (lane==0){ asrc[w]=s; adst[w]=d; }
}

// ---------------- GAT aggregation (h bf16 in, bf16 out): one wave per (node, head)
// softmax without max-subtraction (logits are O(1), f32 exp cannot overflow)
template<int H>
__global__ void agg_kernel(const unsigned short* __restrict__ h,
                           const float* __restrict__ asrc,
                           const float* __restrict__ adst,
                           const float* __restrict__ bias,
                           const int* __restrict__ rp,
                           const int* __restrict__ col,
                           unsigned short* __restrict__ outb, int N){
  const int C = 128;
  int lane = threadIdx.x & 63;
  int w = blockIdx.x*4 + (threadIdx.x >> 6);
  if (w >= N*H) return;
  int n = w / H, hh = w % H;
  int beg = rp[n], end = rp[n+1];
  float adst_i = adst[w];
  float s_self = lrelu02(asrc[w] + adst_i);
  float ssum = (lane==0)? __expf(s_self) : 0.f;
  for (int e = beg+lane; e < end; e += 64)
    ssum += __expf(lrelu02(asrc[col[e]*H + hh] + adst_i));
  ssum = wave_reduce_sum(ssum);
  float inv = 1.f / fmaxf(ssum, 1e-16f);
  const unsigned int* hp = (const unsigned int*)(h + (size_t)w*C);
  unsigned int us = hp[lane];
  float wself = __expf(s_self) * inv;
  float acc0 = b2f(us & 0xffffu)*wself, acc1 = b2f(us >> 16)*wself;

  int e = beg;
  for (; e + 4 <= end; e += 4){
    int r0 = col[e]*H+hh, r1 = col[e+1]*H+hh, r2 = col[e+2]*H+hh, r3 = col[e+3]*H+hh;
    const unsigned int* q0 = (const unsigned int*)(h + (size_t)r0*C);
    const unsigned int* q1 = (const unsigned int*)(h + (size_t)r1*C);
    const unsigned int* q2 = (const unsigned int*)(h + (size_t)r2*C);
    const unsigned int* q3 = (const unsigned int*)(h + (size_t)r3*C);
    unsigned int u0 = q0[lane], u1 = q1[lane], u2 = q2[lane], u3 = q3[lane];
    float s0 = asrc[r0], s1 = asrc[r1], s2 = asrc[r2], s3 = asrc[r3];
    float w0 = __expf(lrelu02(s0 + adst_i)) * inv;
    float w1 = __expf(lrelu02(s1 + adst_i)) * inv;
    float w2 = __expf(lrelu02(s2 + adst_i)) * inv;
    float w3 = __expf(lrelu02(s3 + adst_i)) * inv;
    acc0 += b2f(u0 & 0xffffu)*w0; acc1 += b2f(u0 >> 16)*w0;
    acc0 += b2f(u1 & 0xffffu)*w1; acc1 += b2f(u1 >> 16)*w1;
    acc0 += b2f(u2 & 0xffffu)*w2; acc1 += b2f(u2 >> 16)*w2;
    acc0 += b2f(u3 & 0xffffu)*w3; acc1 += b2f(u3 >> 16)*w3;
  }
  for (; e < end; ++e){
    int r0 = col[e]*H+hh;
    const unsigned int* q0 = (const unsigned int*)(h + (size_t)r0*C);
    unsigned int u0 = q0[lane];
    float w0 = __expf(lrelu02(asrc[r0] + adst_i)) * inv;
    acc0 += b2f(u0 & 0xffffu)*w0; acc1 += b2f(u0 >> 16)*w0;
  }
  int c0 = 2*lane;
  float o0 = elu1(acc0 + bias[hh*C+c0]);
  float o1 = elu1(acc1 + bias[hh*C+c0+1]);
  ((unsigned int*)outb)[(size_t)w*(C/2) + lane] = packbf(o0, o1);
}

// ---------------- edge MLP feats: bf16 in (out2b), bf16 out, K padded to 160
__global__ void feats_kernel(const unsigned short* __restrict__ hf, const int* __restrict__ eli,
                             const float* __restrict__ attr, unsigned short* __restrict__ feats, int E){
  int lane = threadIdx.x & 63;
  int e = blockIdx.x*4 + (threadIdx.x >> 6);
  if (e >= E) return;
  int s = eli[e], d = eli[E+e];
  const unsigned int* hs = (const unsigned int*)(hf + (size_t)s*128);
  const unsigned int* hd = (const unsigned int*)(hf + (size_t)d*128);
  unsigned int us = hs[lane], ud = hd[lane];
  float p0 = b2f(us & 0xffffu) * b2f(ud & 0xffffu);
  float p1 = b2f(us >> 16)     * b2f(ud >> 16);
  unsigned int* ft = (unsigned int*)(feats + (size_t)e*160);
  ft[lane] = packbf(p0, p1);
  if (lane < 8){
    float a0 = attr[(size_t)e*16 + 2*lane], a1 = attr[(size_t)e*16 + 2*lane + 1];
    ft[64+lane] = packbf(a0, a1);
  } else if (lane < 16){
    ft[64+lane] = 0u;
  }
}

// ---------------- final 64->2 layer ----------------
__global__ void mlp2_kernel(const float* __restrict__ hidden, const float* __restrict__ w2,
                            const float* __restrict__ b2, float* __restrict__ out, int E){
  int lane = threadIdx.x & 63;
  int e = blockIdx.x*4 + (threadIdx.x >> 6);
  if (e >= E) return;
  float hv = hidden[(size_t)e*64 + lane];
  float p0 = hv * w2[lane*2+0];
  float p1 = hv * w2[lane*2+1];
  p0 = wave_reduce_sum(p0);
  p1 = wave_reduce_sum(p1);
  if (lane==0){
    out[(size_t)e*2+0] = p0 + b2[0];
    out[(size_t)e*2+1] = p1 + b2[1];
  }
}

extern "C" void kernel_launch(void* const* d_in, const int* in_sizes, int n_in,
                              void* d_out, int out_size, void* d_ws, size_t ws_size,
                              hipStream_t stream){
  const float* x    = (const float*)d_in[0];
  const int*   ei   = (const int*)d_in[1];
  const int*   eli  = (const int*)d_in[3];
  const float* attr = (const float*)d_in[4];
  const float* W1   = (const float*)d_in[5];
  const float* as1  = (const float*)d_in[6];
  const float* ad1  = (const float*)d_in[7];
  const float* b1   = (const float*)d_in[8];
  const float* W2   = (const float*)d_in[9];
  const float* as2  = (const float*)d_in[10];
  const float* ad2  = (const float*)d_in[11];
  const float* b2   = (const float*)d_in[12];
  const float* mw1  = (const float*)d_in[13];
  const float* mb1  = (const float*)d_in[14];
  const float* mw2  = (const float*)d_in[15];
  const float* mb2  = (const float*)d_in[16];
  float* out = (float*)d_out;

  const int N  = in_sizes[0]/128;   // 10000
  const int E  = in_sizes[1]/2;     // 160000
  const int EL = in_sizes[3]/2;     // 100000
  const int H1 = 4, C = 128;
  const int K1 = 128, N1 = 512;
  const int K2 = 512, N2 = 128;
  const int K3 = 160, N3 = 64;

  // ---- workspace layout: live-small-buffers first, then phase-overlay region
  char* ws = (char*)d_ws;
  auto al = [](size_t x){ return (x + 255) & ~(size_t)255; };
  size_t off = 0;
  unsigned short* W1t  = (unsigned short*)(ws + off); off += al((size_t)N1*K1*2);
  unsigned short* W2t  = (unsigned short*)(ws + off); off += al((size_t)N2*K2*2);
  unsigned short* mw1t = (unsigned short*)(ws + off); off += al((size_t)N3*K3*2);
  float* asrc1 = (float*)(ws + off); off += al((size_t)N*H1*4);
  float* adst1 = (float*)(ws + off); off += al((size_t)N*H1*4);
  float* asrc2 = (float*)(ws + off); off += al((size_t)N*4);
  float* adst2 = (float*)(ws + off); off += al((size_t)N*4);
  int* cnt = (int*)(ws + off); off += al((size_t)N*4);
  int* rp  = (int*)(ws + off); off += al((size_t)(N+1)*4);
  int* fl  = (int*)(ws + off); off += al((size_t)N*4);
  int* col = (int*)(ws + off); off += al((size_t)E*4);
  unsigned short* out2b = (unsigned short*)(ws + off); off += al((size_t)N*C*2);
  // phase-1 chain (all dead before feats runs):
  size_t A0 = off;
  unsigned short* xb    = (unsigned short*)(ws + A0);
  unsigned short* h1    = (unsigned short*)(ws + A0 + al((size_t)N*K1*2));
  unsigned short* out1b = (unsigned short*)((char*)h1 + al((size_t)N*N1*2));
  float*          part  = (float*)((char*)out1b + al((size_t)N*N1*2));
  unsigned short* h2b   = (unsigned short*)((char*)part + al((size_t)4*N*N2*4));
  // phase-2 overlay (feats/hidden reuse the dead phase-1 region):
  unsigned short* featsb = (unsigned short*)(ws + A0);
  float*          hidden = (float*)(ws + A0 + al((size_t)EL*160*2));

  // ---- CSR build ----
  hipMemsetAsync(cnt, 0, (size_t)N*4, stream);
  hipMemsetAsync(fl,  0, (size_t)N*4, stream);
  hist_kernel<<<(E+255)/256, 256, 0, stream>>>(ei, cnt, E);
  scan_kernel<<<1, 1024, 0, stream>>>(cnt, rp, N);
  fill_kernel<<<(E+255)/256, 256, 0, stream>>>(ei, rp, fl, col, E);

  // ---- conversions ----
  f2b_kernel<<<(N*K1/4+255)/256, 256, 0, stream>>>(x, xb, N*K1);
  wtrans_kernel<<<(N1*K1+255)/256, 256, 0, stream>>>(W1, W1t, K1, N1, K1);
  wtrans_kernel<<<(N2*K2+255)/256, 256, 0, stream>>>(W2, W2t, K2, N2, K2);
  wtrans_kernel<<<(N3*K3+255)/256, 256, 0, stream>>>(mw1, mw1t, 144, N3, K3);

  // ---- GAT layer 1 ----
  mgemm_kernel<128,1,0,0,1><<<dim3(N1/128, (N+127)/128, 1), 256, 0, stream>>>(
      xb, W1t, nullptr, h1, N, N1, K1);
  attn_kernel<4><<<(N*H1+3)/4, 256, 0, stream>>>(h1, as1, ad1, asrc1, adst1, N);
  agg_kernel<4><<<(N*H1+3)/4, 256, 0, stream>>>(h1, asrc1, adst1, b1, rp, col, out1b, N);

  // ---- GAT layer 2 (splitK=4) ----
  mgemm_kernel<128,4,0,0,0><<<dim3(1, (N+127)/128, 4), 256, 0, stream>>>(
      out1b, W2t, nullptr, part, N, N2, K2);
  reduce4b_kernel<<<(N*N2/4+255)/256, 256, 0, stream>>>(
      (const float4*)part, (uint2*)h2b, N*N2/4, N*N2/4);
  attn_kernel<1><<<(N+3)/4, 256, 0, stream>>>(h2b, as2, ad2, asrc2, adst2, N);
  agg_kernel<1><<<(N+3)/4, 256, 0, stream>>>(h2b, asrc2, adst2, b2, rp, col, out2b, N);

  // ---- edge MLP ----
  feats_kernel<<<(EL+3)/4, 256, 0, stream>>>(out2b, eli, attr, featsb, EL);
  mgemm_kernel<64,1,1,1,0><<<dim3(1, (EL+127)/128, 1), 256, 0, stream>>>(
      featsb, mw1t, mb1, hidden, EL, N3, K3);
  mlp2_kernel<<<(EL+3)/4, 256, 0, stream>>>(hidden, mw2, mb2, out, EL);
}

// Round 7
// 184.458 us; speedup vs baseline: 2.1698x; 1.0255x over previous
//
#include <hip/hip_runtime.h>
#include <hip/hip_bf16.h>
#include <cstdint>

typedef __attribute__((ext_vector_type(8))) short bf16x8;
typedef __attribute__((ext_vector_type(4))) float f32x4;

__device__ __forceinline__ float lrelu02(float x){ return x > 0.f ? x : 0.2f*x; }
__device__ __forceinline__ float elu1(float x){ return x > 0.f ? x : __expf(x)-1.f; }
__device__ __forceinline__ unsigned short bf16_rne(float f){
  unsigned int u = __float_as_uint(f);
  u += 0x7FFFu + ((u >> 16) & 1u);
  return (unsigned short)(u >> 16);
}
__device__ __forceinline__ float b2f(unsigned int hi16){ return __uint_as_float(hi16 << 16); }
__device__ __forceinline__ unsigned int packbf(float a, float b){
  return (unsigned int)bf16_rne(a) | ((unsigned int)bf16_rne(b) << 16);
}

__device__ __forceinline__ float wave_reduce_sum(float v){
  #pragma unroll
  for (int o = 32; o >= 1; o >>= 1) v += __shfl_xor(v, o, 64);
  return v;
}

// ---------------- CSR build ----------------
__global__ void hist_kernel(const int* __restrict__ ei, int* __restrict__ cnt, int E){
  int e = blockIdx.x*blockDim.x + threadIdx.x;
  if (e < E) atomicAdd(&cnt[ei[E + e]], 1);
}

__global__ void scan_kernel(const int* __restrict__ cnt, int* __restrict__ rp, int N){
  __shared__ int part[1024];
  const int PER = 16;
  int t = threadIdx.x;
  int base = t*PER;
  int local[PER]; int s = 0;
  #pragma unroll
  for (int i=0;i<PER;i++){ int idx=base+i; int v = (idx<N)? cnt[idx] : 0; local[i]=s; s+=v; }
  part[t]=s; __syncthreads();
  for (int off=1; off<1024; off<<=1){
    int v = (t>=off)? part[t-off] : 0;
    __syncthreads();
    part[t] += v;
    __syncthreads();
  }
  int ex = (t>0)? part[t-1] : 0;
  #pragma unroll
  for (int i=0;i<PER;i++){ int idx=base+i; if (idx<N) rp[idx] = ex + local[i]; }
  if (t==0) rp[N] = part[1023];
}

__global__ void fill_kernel(const int* __restrict__ ei, const int* __restrict__ rp,
                            int* __restrict__ fl, int* __restrict__ col, int E){
  int e = blockIdx.x*blockDim.x + threadIdx.x;
  if (e >= E) return;
  int d = ei[E+e];
  int pos = rp[d] + atomicAdd(&fl[d], 1);
  col[pos] = ei[e];
}

// ---------------- conversions ----------------
__global__ void f2b_kernel(const float* __restrict__ in, unsigned short* __restrict__ out, int n){
  int i = (blockIdx.x*256 + threadIdx.x)*4;
  if (i >= n) return;
  float4 v = *(const float4*)(in + i);
  out[i+0] = bf16_rne(v.x); out[i+1] = bf16_rne(v.y);
  out[i+2] = bf16_rne(v.z); out[i+3] = bf16_rne(v.w);
}

// W [K][N] f32 -> Wt [N][Kpad] bf16 (zero pad k>=K)
__global__ void wtrans_kernel(const float* __restrict__ W, unsigned short* __restrict__ Wt,
                              int K, int N, int Kpad){
  int idx = blockIdx.x*256 + threadIdx.x;
  if (idx >= N*Kpad) return;
  int n = idx / Kpad, k = idx % Kpad;
  Wt[idx] = (k < K) ? bf16_rne(W[(size_t)k*N + n]) : (unsigned short)0;
}

// ---------------- MFMA bf16 GEMM: C = A[M,K] @ Bt[N,K]^T ----------
// OUTB=1: write bf16 (SPLITK must be 1). OUTB=0: write f32 (+z-sliced for SPLITK).
template<int BN, int SPLITK, int RELU, int WB, int OUTB>
__global__ __launch_bounds__(256) void mgemm_kernel(
    const unsigned short* __restrict__ A,  // [M][K] bf16
    const unsigned short* __restrict__ Bt, // [N][K] bf16
    const float* __restrict__ bias,
    void* __restrict__ C,
    int M, int N, int K){
  const int BM = 128, BK = 32, LDP = BK + 8;
  const int NF = BN/32;
  __shared__ unsigned short As[BM*LDP];
  __shared__ unsigned short Bs[BN*LDP];
  int tid = threadIdx.x;
  int lane = tid & 63, wid = tid >> 6;
  int wr = wid >> 1, wc = wid & 1;
  int row0 = blockIdx.y*BM, col0 = blockIdx.x*BN;
  int kchunk = K / SPLITK;
  int k0base = blockIdx.z * kchunk;
  f32x4 acc[4][NF];
  #pragma unroll
  for (int m=0;m<4;m++)
    #pragma unroll
    for (int n=0;n<NF;n++) acc[m][n] = (f32x4){0.f,0.f,0.f,0.f};

  for (int kt = 0; kt < kchunk; kt += BK){
    int k0 = k0base + kt;
    #pragma unroll
    for (int i=0;i<(BM*4)/256;i++){
      int li = i*256 + tid;
      int r = li >> 2, q = li & 3;
      int gr = row0 + r;
      uint4 v = make_uint4(0u,0u,0u,0u);
      if (gr < M) v = *(const uint4*)(A + (size_t)gr*K + k0 + q*8);
      *(uint4*)(&As[r*LDP + q*8]) = v;
    }
    #pragma unroll
    for (int i=0;i<(BN*4)/256;i++){
      int li = i*256 + tid;
      int r = li >> 2, q = li & 3;
      int gn = col0 + r;
      uint4 v = make_uint4(0u,0u,0u,0u);
      if (gn < N) v = *(const uint4*)(Bt + (size_t)gn*K + k0 + q*8);
      *(uint4*)(&Bs[r*LDP + q*8]) = v;
    }
    __syncthreads();
    int kq = (lane >> 4) * 8;
    bf16x8 af[4], bfr[NF];
    #pragma unroll
    for (int m=0;m<4;m++)
      af[m] = *(const bf16x8*)(&As[(wr*64 + m*16 + (lane&15))*LDP + kq]);
    #pragma unroll
    for (int n=0;n<NF;n++)
      bfr[n] = *(const bf16x8*)(&Bs[(wc*(BN/2) + n*16 + (lane&15))*LDP + kq]);
    #pragma unroll
    for (int m=0;m<4;m++)
      #pragma unroll
      for (int n=0;n<NF;n++)
        acc[m][n] = __builtin_amdgcn_mfma_f32_16x16x32_bf16(af[m], bfr[n], acc[m][n], 0, 0, 0);
    __syncthreads();
  }
  #pragma unroll
  for (int m=0;m<4;m++){
    #pragma unroll
    for (int j=0;j<4;j++){
      int r = row0 + wr*64 + m*16 + (lane>>4)*4 + j;
      if (r >= M) continue;
      #pragma unroll
      for (int n=0;n<NF;n++){
        int c = col0 + wc*(BN/2) + n*16 + (lane&15);
        float v = acc[m][n][j];
        if (WB) v += bias[c];
        if (RELU) v = fmaxf(v, 0.f);
        if (OUTB){
          ((unsigned short*)C)[(size_t)r*N + c] = bf16_rne(v);
        } else {
          float* Cb = (float*)C + (size_t)blockIdx.z * M * N;
          Cb[(size_t)r*N + c] = v;
        }
      }
    }
  }
}

// sum 4 split-K partials -> bf16
__global__ void reduce4b_kernel(const float4* __restrict__ p, uint2* __restrict__ o, int n4, int s4){
  int i = blockIdx.x*256 + threadIdx.x;
  if (i >= n4) return;
  float4 a = p[i], b = p[i+s4], c = p[i+2*s4], d = p[i+3*s4];
  float rx = a.x+b.x+c.x+d.x, ry = a.y+b.y+c.y+d.y;
  float rz = a.z+b.z+c.z+d.z, rw = a.w+b.w+c.w+d.w;
  o[i] = make_uint2(packbf(rx, ry), packbf(rz, rw));
}

// ---------------- attention coefficients (h in bf16): one wave per (node, head)
template<int H>
__global__ void attn_kernel(const unsigned short* __restrict__ h,
                            const float* __restrict__ att_src,
                            const float* __restrict__ att_dst,
                            float* __restrict__ asrc, float* __restrict__ adst, int N){
  const int C = 128;
  int lane = threadIdx.x & 63;
  int w = blockIdx.x*4 + (threadIdx.x >> 6);
  if (w >= N*H) return;
  int hh = w % H;
  const unsigned int* hp = (const unsigned int*)(h + (size_t)w*C);
  unsigned int u = hp[lane];
  float v0 = b2f(u & 0xffffu), v1 = b2f(u >> 16);
  int c0 = 2*lane;
  float s = v0*att_src[hh*C+c0] + v1*att_src[hh*C+c0+1];
  float d = v0*att_dst[hh*C+c0] + v1*att_dst[hh*C+c0+1];
  s = wave_reduce_sum(s); d = wave_reduce_sum(d);
  if (lane==0){ asrc[w]=s; adst[w]=d; }
}

// ---------------- GAT aggregation, SINGLE PASS (h bf16 in, bf16 out)
// acc = sum_e w_e * h[src_e]; wsum = sum_e w_e (wave-uniform, no reduce); out = acc/wsum
template<int H>
__global__ void agg_kernel(const unsigned short* __restrict__ h,
                           const float* __restrict__ asrc,
                           const float* __restrict__ adst,
                           const float* __restrict__ bias,
                           const int* __restrict__ rp,
                           const int* __restrict__ col,
                           unsigned short* __restrict__ outb, int N){
  const int C = 128;
  int lane = threadIdx.x & 63;
  int w = blockIdx.x*4 + (threadIdx.x >> 6);
  if (w >= N*H) return;
  int n = w / H, hh = w % H;
  int beg = rp[n], end = rp[n+1];
  float adst_i = adst[w];
  float wself = __expf(lrelu02(asrc[w] + adst_i));
  const unsigned int* hp = (const unsigned int*)(h + (size_t)w*C);
  unsigned int us = hp[lane];
  float acc0 = b2f(us & 0xffffu)*wself, acc1 = b2f(us >> 16)*wself;
  float wsum = wself;

  int e = beg;
  for (; e + 4 <= end; e += 4){
    int r0 = col[e]*H+hh, r1 = col[e+1]*H+hh, r2 = col[e+2]*H+hh, r3 = col[e+3]*H+hh;
    const unsigned int* q0 = (const unsigned int*)(h + (size_t)r0*C);
    const unsigned int* q1 = (const unsigned int*)(h + (size_t)r1*C);
    const unsigned int* q2 = (const unsigned int*)(h + (size_t)r2*C);
    const unsigned int* q3 = (const unsigned int*)(h + (size_t)r3*C);
    unsigned int u0 = q0[lane], u1 = q1[lane], u2 = q2[lane], u3 = q3[lane];
    float s0 = asrc[r0], s1 = asrc[r1], s2 = asrc[r2], s3 = asrc[r3];
    float w0 = __expf(lrelu02(s0 + adst_i));
    float w1 = __expf(lrelu02(s1 + adst_i));
    float w2 = __expf(lrelu02(s2 + adst_i));
    float w3 = __expf(lrelu02(s3 + adst_i));
    wsum += w0 + w1 + w2 + w3;
    acc0 += b2f(u0 & 0xffffu)*w0; acc1 += b2f(u0 >> 16)*w0;
    acc0 += b2f(u1 & 0xffffu)*w1; acc1 += b2f(u1 >> 16)*w1;
    acc0 += b2f(u2 & 0xffffu)*w2; acc1 += b2f(u2 >> 16)*w2;
    acc0 += b2f(u3 & 0xffffu)*w3; acc1 += b2f(u3 >> 16)*w3;
  }
  for (; e < end; ++e){
    int r0 = col[e]*H+hh;
    const unsigned int* q0 = (const unsigned int*)(h + (size_t)r0*C);
    unsigned int u0 = q0[lane];
    float w0 = __expf(lrelu02(asrc[r0] + adst_i));
    wsum += w0;
    acc0 += b2f(u0 & 0xffffu)*w0; acc1 += b2f(u0 >> 16)*w0;
  }
  float inv = 1.f / fmaxf(wsum, 1e-16f);
  int c0 = 2*lane;
  float o0 = elu1(acc0*inv + bias[hh*C+c0]);
  float o1 = elu1(acc1*inv + bias[hh*C+c0+1]);
  ((unsigned int*)outb)[(size_t)w*(C/2) + lane] = packbf(o0, o1);
}

// ---------------- edge MLP feats: bf16 in (out2b), bf16 out, K padded to 160
__global__ void feats_kernel(const unsigned short* __restrict__ hf, const int* __restrict__ eli,
                             const float* __restrict__ attr, unsigned short* __restrict__ feats, int E){
  int lane = threadIdx.x & 63;
  int e = blockIdx.x*4 + (threadIdx.x >> 6);
  if (e >= E) return;
  int s = eli[e], d = eli[E+e];
  const unsigned int* hs = (const unsigned int*)(hf + (size_t)s*128);
  const unsigned int* hd = (const unsigned int*)(hf + (size_t)d*128);
  unsigned int us = hs[lane], ud = hd[lane];
  float p0 = b2f(us & 0xffffu) * b2f(ud & 0xffffu);
  float p1 = b2f(us >> 16)     * b2f(ud >> 16);
  unsigned int* ft = (unsigned int*)(feats + (size_t)e*160);
  ft[lane] = packbf(p0, p1);
  if (lane < 8){
    float a0 = attr[(size_t)e*16 + 2*lane], a1 = attr[(size_t)e*16 + 2*lane + 1];
    ft[64+lane] = packbf(a0, a1);
  } else if (lane < 16){
    ft[64+lane] = 0u;
  }
}

// ---------------- final 64->2 layer (hidden in bf16) ----------------
__global__ void mlp2_kernel(const unsigned short* __restrict__ hidden, const float* __restrict__ w2,
                            const float* __restrict__ b2, float* __restrict__ out, int E){
  int lane = threadIdx.x & 63;
  int e = blockIdx.x*4 + (threadIdx.x >> 6);
  if (e >= E) return;
  float hv = b2f(hidden[(size_t)e*64 + lane]);
  float p0 = hv * w2[lane*2+0];
  float p1 = hv * w2[lane*2+1];
  p0 = wave_reduce_sum(p0);
  p1 = wave_reduce_sum(p1);
  if (lane==0){
    out[(size_t)e*2+0] = p0 + b2[0];
    out[(size_t)e*2+1] = p1 + b2[1];
  }
}

extern "C" void kernel_launch(void* const* d_in, const int* in_sizes, int n_in,
                              void* d_out, int out_size, void* d_ws, size_t ws_size,
                              hipStream_t stream){
  const float* x    = (const float*)d_in[0];
  const int*   ei   = (const int*)d_in[1];
  const int*   eli  = (const int*)d_in[3];
  const float* attr = (const float*)d_in[4];
  const float* W1   = (const float*)d_in[5];
  const float* as1  = (const float*)d_in[6];
  const float* ad1  = (const float*)d_in[7];
  const float* b1   = (const float*)d_in[8];
  const float* W2   = (const float*)d_in[9];
  const float* as2  = (const float*)d_in[10];
  const float* ad2  = (const float*)d_in[11];
  const float* b2   = (const float*)d_in[12];
  const float* mw1  = (const float*)d_in[13];
  const float* mb1  = (const float*)d_in[14];
  const float* mw2  = (const float*)d_in[15];
  const float* mb2  = (const float*)d_in[16];
  float* out = (float*)d_out;

  const int N  = in_sizes[0]/128;   // 10000
  const int E  = in_sizes[1]/2;     // 160000
  const int EL = in_sizes[3]/2;     // 100000
  const int H1 = 4, C = 128;
  const int K1 = 128, N1 = 512;
  const int K2 = 512, N2 = 128;
  const int K3 = 160, N3 = 64;

  // ---- workspace layout: live-small-buffers first, then phase-overlay region
  char* ws = (char*)d_ws;
  auto al = [](size_t x){ return (x + 255) & ~(size_t)255; };
  size_t off = 0;
  unsigned short* W1t  = (unsigned short*)(ws + off); off += al((size_t)N1*K1*2);
  unsigned short* W2t  = (unsigned short*)(ws + off); off += al((size_t)N2*K2*2);
  unsigned short* mw1t = (unsigned short*)(ws + off); off += al((size_t)N3*K3*2);
  float* asrc1 = (float*)(ws + off); off += al((size_t)N*H1*4);
  float* adst1 = (float*)(ws + off); off += al((size_t)N*H1*4);
  float* asrc2 = (float*)(ws + off); off += al((size_t)N*4);
  float* adst2 = (float*)(ws + off); off += al((size_t)N*4);
  int* cnt = (int*)(ws + off); off += al((size_t)N*4);
  int* rp  = (int*)(ws + off); off += al((size_t)(N+1)*4);
  int* fl  = (int*)(ws + off); off += al((size_t)N*4);
  int* col = (int*)(ws + off); off += al((size_t)E*4);
  unsigned short* out2b = (unsigned short*)(ws + off); off += al((size_t)N*C*2);
  // phase-1 chain (all dead before feats runs):
  size_t A0 = off;
  unsigned short* xb    = (unsigned short*)(ws + A0);
  unsigned short* h1    = (unsigned short*)(ws + A0 + al((size_t)N*K1*2));
  unsigned short* out1b = (unsigned short*)((char*)h1 + al((size_t)N*N1*2));
  float*          part  = (float*)((char*)out1b + al((size_t)N*N1*2));
  unsigned short* h2b   = (unsigned short*)((char*)part + al((size_t)4*N*N2*4));
  // phase-2 overlay (feats/hidden reuse the dead phase-1 region):
  unsigned short* featsb = (unsigned short*)(ws + A0);
  unsigned short* hidden = (unsigned short*)(ws + A0 + al((size_t)EL*160*2));

  // ---- CSR build ----
  hipMemsetAsync(cnt, 0, (size_t)N*4, stream);
  hipMemsetAsync(fl,  0, (size_t)N*4, stream);
  hist_kernel<<<(E+255)/256, 256, 0, stream>>>(ei, cnt, E);
  scan_kernel<<<1, 1024, 0, stream>>>(cnt, rp, N);
  fill_kernel<<<(E+255)/256, 256, 0, stream>>>(ei, rp, fl, col, E);

  // ---- conversions ----
  f2b_kernel<<<(N*K1/4+255)/256, 256, 0, stream>>>(x, xb, N*K1);
  wtrans_kernel<<<(N1*K1+255)/256, 256, 0, stream>>>(W1, W1t, K1, N1, K1);
  wtrans_kernel<<<(N2*K2+255)/256, 256, 0, stream>>>(W2, W2t, K2, N2, K2);
  wtrans_kernel<<<(N3*K3+255)/256, 256, 0, stream>>>(mw1, mw1t, 144, N3, K3);

  // ---- GAT layer 1 ----
  mgemm_kernel<128,1,0,0,1><<<dim3(N1/128, (N+127)/128, 1), 256, 0, stream>>>(
      xb, W1t, nullptr, h1, N, N1, K1);
  attn_kernel<4><<<(N*H1+3)/4, 256, 0, stream>>>(h1, as1, ad1, asrc1, adst1, N);
  agg_kernel<4><<<(N*H1+3)/4, 256, 0, stream>>>(h1, asrc1, adst1, b1, rp, col, out1b, N);

  // ---- GAT layer 2 (splitK=4) ----
  mgemm_kernel<128,4,0,0,0><<<dim3(1, (N+127)/128, 4), 256, 0, stream>>>(
      out1b, W2t, nullptr, part, N, N2, K2);
  reduce4b_kernel<<<(N*N2/4+255)/256, 256, 0, stream>>>(
      (const float4*)part, (uint2*)h2b, N*N2/4, N*N2/4);
  attn_kernel<1><<<(N+3)/4, 256, 0, stream>>>(h2b, as2, ad2, asrc2, adst2, N);
  agg_kernel<1><<<(N+3)/4, 256, 0, stream>>>(h2b, asrc2, adst2, b2, rp, col, out2b, N);

  // ---- edge MLP ----
  feats_kernel<<<(EL+3)/4, 256, 0, stream>>>(out2b, eli, attr, featsb, EL);
  mgemm_kernel<64,1,1,1,1><<<dim3(1, (EL+127)/128, 1), 256, 0, stream>>>(
      featsb, mw1t, mb1, hidden, EL, N3, K3);
  mlp2_kernel<<<(EL+3)/4, 256, 0, stream>>>(hidden, mw2, mb2, out, EL);
}

// Round 8
// 164.658 us; speedup vs baseline: 2.4307x; 1.1202x over previous
//
#include <hip/hip_runtime.h>
#include <hip/hip_bf16.h>
#include <cstdint>

typedef __attribute__((ext_vector_type(8))) short bf16x8;
typedef __attribute__((ext_vector_type(4))) float f32x4;

__device__ __forceinline__ float lrelu02(float x){ return x > 0.f ? x : 0.2f*x; }
__device__ __forceinline__ float elu1(float x){ return x > 0.f ? x : __expf(x)-1.f; }
__device__ __forceinline__ unsigned short bf16_rne(float f){
  unsigned int u = __float_as_uint(f);
  u += 0x7FFFu + ((u >> 16) & 1u);
  return (unsigned short)(u >> 16);
}
__device__ __forceinline__ float b2f(unsigned int hi16){ return __uint_as_float(hi16 << 16); }
__device__ __forceinline__ unsigned int packbf(float a, float b){
  return (unsigned int)bf16_rne(a) | ((unsigned int)bf16_rne(b) << 16);
}

__device__ __forceinline__ float wave_reduce_sum(float v){
  #pragma unroll
  for (int o = 32; o >= 1; o >>= 1) v += __shfl_xor(v, o, 64);
  return v;
}

// ---------------- CSR build ----------------
__global__ void hist_kernel(const int* __restrict__ ei, int* __restrict__ cnt, int E){
  int e = blockIdx.x*blockDim.x + threadIdx.x;
  if (e < E) atomicAdd(&cnt[ei[E + e]], 1);
}

__global__ void scan_kernel(const int* __restrict__ cnt, int* __restrict__ rp, int N){
  __shared__ int part[1024];
  const int PER = 16;
  int t = threadIdx.x;
  int base = t*PER;
  int local[PER]; int s = 0;
  #pragma unroll
  for (int i=0;i<PER;i++){ int idx=base+i; int v = (idx<N)? cnt[idx] : 0; local[i]=s; s+=v; }
  part[t]=s; __syncthreads();
  for (int off=1; off<1024; off<<=1){
    int v = (t>=off)? part[t-off] : 0;
    __syncthreads();
    part[t] += v;
    __syncthreads();
  }
  int ex = (t>0)? part[t-1] : 0;
  #pragma unroll
  for (int i=0;i<PER;i++){ int idx=base+i; if (idx<N) rp[idx] = ex + local[i]; }
  if (t==0) rp[N] = part[1023];
}

__global__ void fill_kernel(const int* __restrict__ ei, const int* __restrict__ rp,
                            int* __restrict__ fl, int* __restrict__ col, int E){
  int e = blockIdx.x*blockDim.x + threadIdx.x;
  if (e >= E) return;
  int d = ei[E+e];
  int pos = rp[d] + atomicAdd(&fl[d], 1);
  col[pos] = ei[e];
}

// ---------------- fused conversions: f2b(x) + W1t + W2t + mw1t ----------------
// ranges: [0,320000) f2b 4-wide; [320000,385536) W1t; [385536,451072) W2t; [451072,461312) mw1t
__global__ void conv_all_kernel(const float* __restrict__ x, unsigned short* __restrict__ xb,
                                const float* __restrict__ W1, unsigned short* __restrict__ W1t,
                                const float* __restrict__ W2, unsigned short* __restrict__ W2t,
                                const float* __restrict__ mw1, unsigned short* __restrict__ mw1t){
  int t = blockIdx.x*256 + threadIdx.x;
  if (t < 320000){
    int i = t*4;
    float4 v = *(const float4*)(x + i);
    xb[i+0] = bf16_rne(v.x); xb[i+1] = bf16_rne(v.y);
    xb[i+2] = bf16_rne(v.z); xb[i+3] = bf16_rne(v.w);
  } else if (t < 385536){
    int i = t - 320000;                 // W1 [128][512] -> W1t [512][128]
    int n = i >> 7, k = i & 127;
    W1t[i] = bf16_rne(W1[(size_t)k*512 + n]);
  } else if (t < 451072){
    int i = t - 385536;                 // W2 [512][128] -> W2t [128][512]
    int n = i >> 9, k = i & 511;
    W2t[i] = bf16_rne(W2[(size_t)k*128 + n]);
  } else if (t < 461312){
    int i = t - 451072;                 // mw1 [144][64] -> mw1t [64][160] (pad)
    int n = i / 160, k = i % 160;
    mw1t[i] = (k < 144) ? bf16_rne(mw1[(size_t)k*64 + n]) : (unsigned short)0;
  }
}

// ---------------- MFMA bf16 GEMM: C = A[M,K] @ Bt[N,K]^T ----------
// OUTB=1: write bf16 (SPLITK must be 1). OUTB=0: write f32 (+z-sliced for SPLITK).
template<int BN, int SPLITK, int RELU, int WB, int OUTB>
__global__ __launch_bounds__(256) void mgemm_kernel(
    const unsigned short* __restrict__ A,  // [M][K] bf16
    const unsigned short* __restrict__ Bt, // [N][K] bf16
    const float* __restrict__ bias,
    void* __restrict__ C,
    int M, int N, int K){
  const int BM = 128, BK = 32, LDP = BK + 8;
  const int NF = BN/32;
  __shared__ unsigned short As[BM*LDP];
  __shared__ unsigned short Bs[BN*LDP];
  int tid = threadIdx.x;
  int lane = tid & 63, wid = tid >> 6;
  int wr = wid >> 1, wc = wid & 1;
  int row0 = blockIdx.y*BM, col0 = blockIdx.x*BN;
  int kchunk = K / SPLITK;
  int k0base = blockIdx.z * kchunk;
  f32x4 acc[4][NF];
  #pragma unroll
  for (int m=0;m<4;m++)
    #pragma unroll
    for (int n=0;n<NF;n++) acc[m][n] = (f32x4){0.f,0.f,0.f,0.f};

  for (int kt = 0; kt < kchunk; kt += BK){
    int k0 = k0base + kt;
    #pragma unroll
    for (int i=0;i<(BM*4)/256;i++){
      int li = i*256 + tid;
      int r = li >> 2, q = li & 3;
      int gr = row0 + r;
      uint4 v = make_uint4(0u,0u,0u,0u);
      if (gr < M) v = *(const uint4*)(A + (size_t)gr*K + k0 + q*8);
      *(uint4*)(&As[r*LDP + q*8]) = v;
    }
    #pragma unroll
    for (int i=0;i<(BN*4)/256;i++){
      int li = i*256 + tid;
      int r = li >> 2, q = li & 3;
      int gn = col0 + r;
      uint4 v = make_uint4(0u,0u,0u,0u);
      if (gn < N) v = *(const uint4*)(Bt + (size_t)gn*K + k0 + q*8);
      *(uint4*)(&Bs[r*LDP + q*8]) = v;
    }
    __syncthreads();
    int kq = (lane >> 4) * 8;
    bf16x8 af[4], bfr[NF];
    #pragma unroll
    for (int m=0;m<4;m++)
      af[m] = *(const bf16x8*)(&As[(wr*64 + m*16 + (lane&15))*LDP + kq]);
    #pragma unroll
    for (int n=0;n<NF;n++)
      bfr[n] = *(const bf16x8*)(&Bs[(wc*(BN/2) + n*16 + (lane&15))*LDP + kq]);
    #pragma unroll
    for (int m=0;m<4;m++)
      #pragma unroll
      for (int n=0;n<NF;n++)
        acc[m][n] = __builtin_amdgcn_mfma_f32_16x16x32_bf16(af[m], bfr[n], acc[m][n], 0, 0, 0);
    __syncthreads();
  }
  #pragma unroll
  for (int m=0;m<4;m++){
    #pragma unroll
    for (int j=0;j<4;j++){
      int r = row0 + wr*64 + m*16 + (lane>>4)*4 + j;
      if (r >= M) continue;
      #pragma unroll
      for (int n=0;n<NF;n++){
        int c = col0 + wc*(BN/2) + n*16 + (lane&15);
        float v = acc[m][n][j];
        if (WB) v += bias[c];
        if (RELU) v = fmaxf(v, 0.f);
        if (OUTB){
          ((unsigned short*)C)[(size_t)r*N + c] = bf16_rne(v);
        } else {
          float* Cb = (float*)C + (size_t)blockIdx.z * M * N;
          Cb[(size_t)r*N + c] = v;
        }
      }
    }
  }
}

// sum 4 split-K partials -> bf16
__global__ void reduce4b_kernel(const float4* __restrict__ p, uint2* __restrict__ o, int n4, int s4){
  int i = blockIdx.x*256 + threadIdx.x;
  if (i >= n4) return;
  float4 a = p[i], b = p[i+s4], c = p[i+2*s4], d = p[i+3*s4];
  float rx = a.x+b.x+c.x+d.x, ry = a.y+b.y+c.y+d.y;
  float rz = a.z+b.z+c.z+d.z, rw = a.w+b.w+c.w+d.w;
  o[i] = make_uint2(packbf(rx, ry), packbf(rz, rw));
}

// ---------------- layer-1 attention coefficients, head-merged: one wave per node
// h [N][512] bf16; lane covers 8 channels ch=lane*8 of head hh=lane>>4.
__global__ void attn4_kernel(const unsigned short* __restrict__ h,
                             const float* __restrict__ att_src,   // [512]
                             const float* __restrict__ att_dst,
                             float* __restrict__ asrc, float* __restrict__ adst, int N){
  int lane = threadIdx.x & 63;
  int n = blockIdx.x*4 + (threadIdx.x >> 6);
  if (n >= N) return;
  const uint4* hp = (const uint4*)(h + (size_t)n*512);
  uint4 u = hp[lane];
  int ch = lane*8;
  float f0 = b2f(u.x & 0xffffu), f1 = b2f(u.x >> 16);
  float f2 = b2f(u.y & 0xffffu), f3 = b2f(u.y >> 16);
  float f4 = b2f(u.z & 0xffffu), f5 = b2f(u.z >> 16);
  float f6 = b2f(u.w & 0xffffu), f7 = b2f(u.w >> 16);
  float s = f0*att_src[ch+0] + f1*att_src[ch+1] + f2*att_src[ch+2] + f3*att_src[ch+3]
          + f4*att_src[ch+4] + f5*att_src[ch+5] + f6*att_src[ch+6] + f7*att_src[ch+7];
  float d = f0*att_dst[ch+0] + f1*att_dst[ch+1] + f2*att_dst[ch+2] + f3*att_dst[ch+3]
          + f4*att_dst[ch+4] + f5*att_dst[ch+5] + f6*att_dst[ch+6] + f7*att_dst[ch+7];
  #pragma unroll
  for (int o=1; o<16; o<<=1){ s += __shfl_xor(s, o, 64); d += __shfl_xor(d, o, 64); }
  if ((lane & 15) == 0){
    int hh = lane >> 4;
    asrc[n*4 + hh] = s; adst[n*4 + hh] = d;
  }
}

// ---------------- layer-1 aggregation, head-merged single pass: one wave per node
// lane owns 8 channels of head hh=lane>>4; weights computed per-lane for its head.
__global__ void agg4_kernel(const unsigned short* __restrict__ h,   // [N][512]
                            const float* __restrict__ asrc,         // [N][4]
                            const float* __restrict__ adst,
                            const float* __restrict__ bias,         // [512]
                            const int* __restrict__ rp,
                            const int* __restrict__ col,
                            unsigned short* __restrict__ outb, int N){
  int lane = threadIdx.x & 63;
  int n = blockIdx.x*4 + (threadIdx.x >> 6);
  if (n >= N) return;
  int hh = lane >> 4;
  int beg = rp[n], end = rp[n+1];
  float adst_i = adst[n*4 + hh];
  float wself = __expf(lrelu02(asrc[n*4 + hh] + adst_i));
  const uint4* hp = (const uint4*)(h + (size_t)n*512);
  uint4 us = hp[lane];
  float a0 = b2f(us.x & 0xffffu)*wself, a1 = b2f(us.x >> 16)*wself;
  float a2 = b2f(us.y & 0xffffu)*wself, a3 = b2f(us.y >> 16)*wself;
  float a4 = b2f(us.z & 0xffffu)*wself, a5 = b2f(us.z >> 16)*wself;
  float a6 = b2f(us.w & 0xffffu)*wself, a7 = b2f(us.w >> 16)*wself;
  float wsum = wself;

  int e = beg;
  for (; e + 4 <= end; e += 4){
    int s0 = col[e], s1 = col[e+1], s2 = col[e+2], s3 = col[e+3];
    const uint4* q0 = (const uint4*)(h + (size_t)s0*512);
    const uint4* q1 = (const uint4*)(h + (size_t)s1*512);
    const uint4* q2 = (const uint4*)(h + (size_t)s2*512);
    const uint4* q3 = (const uint4*)(h + (size_t)s3*512);
    uint4 u0 = q0[lane], u1 = q1[lane], u2 = q2[lane], u3 = q3[lane];
    float w0 = __expf(lrelu02(asrc[s0*4 + hh] + adst_i));
    float w1 = __expf(lrelu02(asrc[s1*4 + hh] + adst_i));
    float w2 = __expf(lrelu02(asrc[s2*4 + hh] + adst_i));
    float w3 = __expf(lrelu02(asrc[s3*4 + hh] + adst_i));
    wsum += w0 + w1 + w2 + w3;
    a0 += b2f(u0.x & 0xffffu)*w0; a1 += b2f(u0.x >> 16)*w0;
    a2 += b2f(u0.y & 0xffffu)*w0; a3 += b2f(u0.y >> 16)*w0;
    a4 += b2f(u0.z & 0xffffu)*w0; a5 += b2f(u0.z >> 16)*w0;
    a6 += b2f(u0.w & 0xffffu)*w0; a7 += b2f(u0.w >> 16)*w0;
    a0 += b2f(u1.x & 0xffffu)*w1; a1 += b2f(u1.x >> 16)*w1;
    a2 += b2f(u1.y & 0xffffu)*w1; a3 += b2f(u1.y >> 16)*w1;
    a4 += b2f(u1.z & 0xffffu)*w1; a5 += b2f(u1.z >> 16)*w1;
    a6 += b2f(u1.w & 0xffffu)*w1; a7 += b2f(u1.w >> 16)*w1;
    a0 += b2f(u2.x & 0xffffu)*w2; a1 += b2f(u2.x >> 16)*w2;
    a2 += b2f(u2.y & 0xffffu)*w2; a3 += b2f(u2.y >> 16)*w2;
    a4 += b2f(u2.z & 0xffffu)*w2; a5 += b2f(u2.z >> 16)*w2;
    a6 += b2f(u2.w & 0xffffu)*w2; a7 += b2f(u2.w >> 16)*w2;
    a0 += b2f(u3.x & 0xffffu)*w3; a1 += b2f(u3.x >> 16)*w3;
    a2 += b2f(u3.y & 0xffffu)*w3; a3 += b2f(u3.y >> 16)*w3;
    a4 += b2f(u3.z & 0xffffu)*w3; a5 += b2f(u3.z >> 16)*w3;
    a6 += b2f(u3.w & 0xffffu)*w3; a7 += b2f(u3.w >> 16)*w3;
  }
  for (; e < end; ++e){
    int s0 = col[e];
    const uint4* q0 = (const uint4*)(h + (size_t)s0*512);
    uint4 u0 = q0[lane];
    float w0 = __expf(lrelu02(asrc[s0*4 + hh] + adst_i));
    wsum += w0;
    a0 += b2f(u0.x & 0xffffu)*w0; a1 += b2f(u0.x >> 16)*w0;
    a2 += b2f(u0.y & 0xffffu)*w0; a3 += b2f(u0.y >> 16)*w0;
    a4 += b2f(u0.z & 0xffffu)*w0; a5 += b2f(u0.z >> 16)*w0;
    a6 += b2f(u0.w & 0xffffu)*w0; a7 += b2f(u0.w >> 16)*w0;
  }
  float inv = 1.f / fmaxf(wsum, 1e-16f);
  int ch = lane*8;
  float o0 = elu1(a0*inv + bias[ch+0]);
  float o1 = elu1(a1*inv + bias[ch+1]);
  float o2 = elu1(a2*inv + bias[ch+2]);
  float o3 = elu1(a3*inv + bias[ch+3]);
  float o4 = elu1(a4*inv + bias[ch+4]);
  float o5 = elu1(a5*inv + bias[ch+5]);
  float o6 = elu1(a6*inv + bias[ch+6]);
  float o7 = elu1(a7*inv + bias[ch+7]);
  ((uint4*)(outb + (size_t)n*512))[lane] =
      make_uint4(packbf(o0,o1), packbf(o2,o3), packbf(o4,o5), packbf(o6,o7));
}

// ---------------- layer-2 (H=1) attention: one wave per node ----------------
__global__ void attn1_kernel(const unsigned short* __restrict__ h,
                             const float* __restrict__ att_src,
                             const float* __restrict__ att_dst,
                             float* __restrict__ asrc, float* __restrict__ adst, int N){
  const int C = 128;
  int lane = threadIdx.x & 63;
  int w = blockIdx.x*4 + (threadIdx.x >> 6);
  if (w >= N) return;
  const unsigned int* hp = (const unsigned int*)(h + (size_t)w*C);
  unsigned int u = hp[lane];
  float v0 = b2f(u & 0xffffu), v1 = b2f(u >> 16);
  int c0 = 2*lane;
  float s = v0*att_src[c0] + v1*att_src[c0+1];
  float d = v0*att_dst[c0] + v1*att_dst[c0+1];
  s = wave_reduce_sum(s); d = wave_reduce_sum(d);
  if (lane==0){ asrc[w]=s; adst[w]=d; }
}

// ---------------- layer-2 (H=1) aggregation, single pass ----------------
__global__ void agg1_kernel(const unsigned short* __restrict__ h,
                            const float* __restrict__ asrc,
                            const float* __restrict__ adst,
                            const float* __restrict__ bias,
                            const int* __restrict__ rp,
                            const int* __restrict__ col,
                            unsigned short* __restrict__ outb, int N){
  const int C = 128;
  int lane = threadIdx.x & 63;
  int n = blockIdx.x*4 + (threadIdx.x >> 6);
  if (n >= N) return;
  int beg = rp[n], end = rp[n+1];
  float adst_i = adst[n];
  float wself = __expf(lrelu02(asrc[n] + adst_i));
  const unsigned int* hp = (const unsigned int*)(h + (size_t)n*C);
  unsigned int us = hp[lane];
  float acc0 = b2f(us & 0xffffu)*wself, acc1 = b2f(us >> 16)*wself;
  float wsum = wself;

  int e = beg;
  for (; e + 4 <= end; e += 4){
    int r0 = col[e], r1 = col[e+1], r2 = col[e+2], r3 = col[e+3];
    const unsigned int* q0 = (const unsigned int*)(h + (size_t)r0*C);
    const unsigned int* q1 = (const unsigned int*)(h + (size_t)r1*C);
    const unsigned int* q2 = (const unsigned int*)(h + (size_t)r2*C);
    const unsigned int* q3 = (const unsigned int*)(h + (size_t)r3*C);
    unsigned int u0 = q0[lane], u1 = q1[lane], u2 = q2[lane], u3 = q3[lane];
    float w0 = __expf(lrelu02(asrc[r0] + adst_i));
    float w1 = __expf(lrelu02(asrc[r1] + adst_i));
    float w2 = __expf(lrelu02(asrc[r2] + adst_i));
    float w3 = __expf(lrelu02(asrc[r3] + adst_i));
    wsum += w0 + w1 + w2 + w3;
    acc0 += b2f(u0 & 0xffffu)*w0; acc1 += b2f(u0 >> 16)*w0;
    acc0 += b2f(u1 & 0xffffu)*w1; acc1 += b2f(u1 >> 16)*w1;
    acc0 += b2f(u2 & 0xffffu)*w2; acc1 += b2f(u2 >> 16)*w2;
    acc0 += b2f(u3 & 0xffffu)*w3; acc1 += b2f(u3 >> 16)*w3;
  }
  for (; e < end; ++e){
    int r0 = col[e];
    const unsigned int* q0 = (const unsigned int*)(h + (size_t)r0*C);
    unsigned int u0 = q0[lane];
    float w0 = __expf(lrelu02(asrc[r0] + adst_i));
    wsum += w0;
    acc0 += b2f(u0 & 0xffffu)*w0; acc1 += b2f(u0 >> 16)*w0;
  }
  float inv = 1.f / fmaxf(wsum, 1e-16f);
  int c0 = 2*lane;
  float o0 = elu1(acc0*inv + bias[c0]);
  float o1 = elu1(acc1*inv + bias[c0+1]);
  ((unsigned int*)outb)[(size_t)n*(C/2) + lane] = packbf(o0, o1);
}

// ---------------- edge MLP feats: bf16 in, bf16 out, K padded to 160 ----------------
__global__ void feats_kernel(const unsigned short* __restrict__ hf, const int* __restrict__ eli,
                             const float* __restrict__ attr, unsigned short* __restrict__ feats, int E){
  int lane = threadIdx.x & 63;
  int e = blockIdx.x*4 + (threadIdx.x >> 6);
  if (e >= E) return;
  int s = eli[e], d = eli[E+e];
  const unsigned int* hs = (const unsigned int*)(hf + (size_t)s*128);
  const unsigned int* hd = (const unsigned int*)(hf + (size_t)d*128);
  unsigned int us = hs[lane], ud = hd[lane];
  float p0 = b2f(us & 0xffffu) * b2f(ud & 0xffffu);
  float p1 = b2f(us >> 16)     * b2f(ud >> 16);
  unsigned int* ft = (unsigned int*)(feats + (size_t)e*160);
  ft[lane] = packbf(p0, p1);
  if (lane < 8){
    float a0 = attr[(size_t)e*16 + 2*lane], a1 = attr[(size_t)e*16 + 2*lane + 1];
    ft[64+lane] = packbf(a0, a1);
  } else if (lane < 16){
    ft[64+lane] = 0u;
  }
}

// ---------------- final 64->2 layer (hidden in bf16) ----------------
__global__ void mlp2_kernel(const unsigned short* __restrict__ hidden, const float* __restrict__ w2,
                            const float* __restrict__ b2, float* __restrict__ out, int E){
  int lane = threadIdx.x & 63;
  int e = blockIdx.x*4 + (threadIdx.x >> 6);
  if (e >= E) return;
  float hv = b2f(hidden[(size_t)e*64 + lane]);
  float p0 = hv * w2[lane*2+0];
  float p1 = hv * w2[lane*2+1];
  p0 = wave_reduce_sum(p0);
  p1 = wave_reduce_sum(p1);
  if (lane==0){
    out[(size_t)e*2+0] = p0 + b2[0];
    out[(size_t)e*2+1] = p1 + b2[1];
  }
}

extern "C" void kernel_launch(void* const* d_in, const int* in_sizes, int n_in,
                              void* d_out, int out_size, void* d_ws, size_t ws_size,
                              hipStream_t stream){
  const float* x    = (const float*)d_in[0];
  const int*   ei   = (const int*)d_in[1];
  const int*   eli  = (const int*)d_in[3];
  const float* attr = (const float*)d_in[4];
  const float* W1   = (const float*)d_in[5];
  const float* as1  = (const float*)d_in[6];
  const float* ad1  = (const float*)d_in[7];
  const float* b1   = (const float*)d_in[8];
  const float* W2   = (const float*)d_in[9];
  const float* as2  = (const float*)d_in[10];
  const float* ad2  = (const float*)d_in[11];
  const float* b2   = (const float*)d_in[12];
  const float* mw1  = (const float*)d_in[13];
  const float* mb1  = (const float*)d_in[14];
  const float* mw2  = (const float*)d_in[15];
  const float* mb2  = (const float*)d_in[16];
  float* out = (float*)d_out;

  const int N  = in_sizes[0]/128;   // 10000
  const int E  = in_sizes[1]/2;     // 160000
  const int EL = in_sizes[3]/2;     // 100000
  const int H1 = 4, C = 128;
  const int K1 = 128, N1 = 512;
  const int K2 = 512, N2 = 128;
  const int K3 = 160, N3 = 64;

  // ---- workspace layout: live-small-buffers first, then phase-overlay region
  char* ws = (char*)d_ws;
  auto al = [](size_t x){ return (x + 255) & ~(size_t)255; };
  size_t off = 0;
  unsigned short* W1t  = (unsigned short*)(ws + off); off += al((size_t)N1*K1*2);
  unsigned short* W2t  = (unsigned short*)(ws + off); off += al((size_t)N2*K2*2);
  unsigned short* mw1t = (unsigned short*)(ws + off); off += al((size_t)N3*K3*2);
  float* asrc1 = (float*)(ws + off); off += al((size_t)N*H1*4);
  float* adst1 = (float*)(ws + off); off += al((size_t)N*H1*4);
  float* asrc2 = (float*)(ws + off); off += al((size_t)N*4);
  float* adst2 = (float*)(ws + off); off += al((size_t)N*4);
  int* cnt = (int*)(ws + off); off += (size_t)N*4;       // cnt+fl adjacent, one memset
  int* fl  = (int*)(ws + off); off += al((size_t)N*4);
  int* rp  = (int*)(ws + off); off += al((size_t)(N+1)*4);
  int* col = (int*)(ws + off); off += al((size_t)E*4);
  unsigned short* out2b = (unsigned short*)(ws + off); off += al((size_t)N*C*2);
  // phase-1 chain (all dead before feats runs):
  size_t A0 = off;
  unsigned short* xb    = (unsigned short*)(ws + A0);
  unsigned short* h1    = (unsigned short*)(ws + A0 + al((size_t)N*K1*2));
  unsigned short* out1b = (unsigned short*)((char*)h1 + al((size_t)N*N1*2));
  float*          part  = (float*)((char*)out1b + al((size_t)N*N1*2));
  unsigned short* h2b   = (unsigned short*)((char*)part + al((size_t)4*N*N2*4));
  // phase-2 overlay (feats/hidden reuse the dead phase-1 region):
  unsigned short* featsb = (unsigned short*)(ws + A0);
  unsigned short* hidden = (unsigned short*)(ws + A0 + al((size_t)EL*160*2));

  // ---- CSR build ----
  hipMemsetAsync(cnt, 0, (size_t)2*N*4, stream);   // zeroes cnt and fl
  hist_kernel<<<(E+255)/256, 256, 0, stream>>>(ei, cnt, E);
  scan_kernel<<<1, 1024, 0, stream>>>(cnt, rp, N);
  fill_kernel<<<(E+255)/256, 256, 0, stream>>>(ei, rp, fl, col, E);

  // ---- fused conversions ----
  conv_all_kernel<<<1803, 256, 0, stream>>>(x, xb, W1, W1t, W2, W2t, mw1, mw1t);

  // ---- GAT layer 1 (BN=64 for occupancy) ----
  mgemm_kernel<64,1,0,0,1><<<dim3(N1/64, (N+127)/128, 1), 256, 0, stream>>>(
      xb, W1t, nullptr, h1, N, N1, K1);
  attn4_kernel<<<(N+3)/4, 256, 0, stream>>>(h1, as1, ad1, asrc1, adst1, N);
  agg4_kernel<<<(N+3)/4, 256, 0, stream>>>(h1, asrc1, adst1, b1, rp, col, out1b, N);

  // ---- GAT layer 2 (BN=64, splitK=4) ----
  mgemm_kernel<64,4,0,0,0><<<dim3(N2/64, (N+127)/128, 4), 256, 0, stream>>>(
      out1b, W2t, nullptr, part, N, N2, K2);
  reduce4b_kernel<<<(N*N2/4+255)/256, 256, 0, stream>>>(
      (const float4*)part, (uint2*)h2b, N*N2/4, N*N2/4);
  attn1_kernel<<<(N+3)/4, 256, 0, stream>>>(h2b, as2, ad2, asrc2, adst2, N);
  agg1_kernel<<<(N+3)/4, 256, 0, stream>>>(h2b, asrc2, adst2, b2, rp, col, out2b, N);

  // ---- edge MLP ----
  feats_kernel<<<(EL+3)/4, 256, 0, stream>>>(out2b, eli, attr, featsb, EL);
  mgemm_kernel<64,1,1,1,1><<<dim3(1, (EL+127)/128, 1), 256, 0, stream>>>(
      featsb, mw1t, mb1, hidden, EL, N3, K3);
  mlp2_kernel<<<(EL+3)/4, 256, 0, stream>>>(hidden, mw2, mb2, out, EL);
}